// Round 18
// baseline (789.789 us; speedup 1.0000x reference)
//
#include <hip/hip_runtime.h>
#include <hip/hip_fp8.h>
#include <stdint.h>

typedef float    f32x4  __attribute__((ext_vector_type(4)));
typedef float    f32x16 __attribute__((ext_vector_type(16)));
typedef int      i32x4  __attribute__((ext_vector_type(4)));
typedef int      i32x8  __attribute__((ext_vector_type(8)));
typedef __bf16   bf16x8 __attribute__((ext_vector_type(8)));
typedef uint16_t u16x8  __attribute__((ext_vector_type(8)));
typedef uint16_t u16x4  __attribute__((ext_vector_type(4)));
typedef uint8_t  u8x4   __attribute__((ext_vector_type(4)));
typedef uint32_t u32x4  __attribute__((ext_vector_type(4)));

static __device__ __forceinline__ f32x4 mfma_bf16(bf16x8 a, bf16x8 b, f32x4 c) {
  return __builtin_amdgcn_mfma_f32_16x16x32_bf16(a, b, c, 0, 0, 0);
}
// fp32 -> bf16 round-to-nearest-even
static __device__ __forceinline__ uint16_t f2bf(float f) {
  uint32_t u = __builtin_bit_cast(uint32_t, f);
  u += 0x7fffu + ((u >> 16) & 1u);
  return (uint16_t)(u >> 16);
}
// fp32 -> fp8 OCP e4m3fn
static __device__ __forceinline__ uint8_t f2fp8(float f) {
  __hip_fp8_e4m3 v(f);
  return v.__x;
}
// async global->LDS, 16B per lane (gfx950). dest must be linear-in-lane.
static __device__ __forceinline__ void gload16(const void* src, void* lds) {
  __builtin_amdgcn_global_load_lds(
      (const __attribute__((address_space(1))) void*)src,
      (__attribute__((address_space(3))) void*)lds, 16, 0, 0);
}

constexpr int Nrows = 131072;
constexpr int Dk    = 128;
constexpr int Cc    = 1024;
constexpr int CH     = 16384;          // rows per chunk (mid-ws fallback)
constexpr int NCHUNK = Nrows / CH;     // 8
// fused fallback (R5) geometry
constexpr int BMf   = 64;
constexpr int BNf   = 256;
constexpr int KBf   = 128;
constexpr int XBYTES = BMf * Dk * 2;
constexpr int PBYTES = BMf * KBf * 2;
constexpr int LDS_MAIN = XBYTES + PBYTES + BMf * 4;
constexpr int LDS_FB   = LDS_MAIN + Cc * 4;
constexpr int KEXP2_LDS = 32768 * 3 + 128 * 144 + 512;   // 116864
constexpr int G2F8_LDS  = 131072 + 2 * 16384;            // 163840 = 160 KB

// ---------------------------------------------------------------------------
// Prep A: centers -> bf16 [C][D], and c2[C]
// ---------------------------------------------------------------------------
__global__ void prep_cen(const float* __restrict__ cen,
                         uint16_t* __restrict__ cenb,
                         float* __restrict__ c2) {
  const int t = threadIdx.x;
  const int row = blockIdx.x * 16 + (t >> 4);
  const int q = t & 15;
  const float* src = cen + (size_t)row * Dk + q * 8;
  f32x4 v0 = *(const f32x4*)src;
  f32x4 v1 = *(const f32x4*)(src + 4);
  u16x8 h;
  float ss = 0.f;
#pragma unroll
  for (int i = 0; i < 4; ++i) {
    h[i]     = f2bf(v0[i]); ss += v0[i] * v0[i];
    h[i + 4] = f2bf(v1[i]); ss += v1[i] * v1[i];
  }
  *(u16x8*)(cenb + (size_t)row * Dk + q * 8) = h;
  ss += __shfl_xor(ss, 1);
  ss += __shfl_xor(ss, 2);
  ss += __shfl_xor(ss, 4);
  ss += __shfl_xor(ss, 8);
  if (q == 0) c2[row] = ss;
}

// ---------------------------------------------------------------------------
// Prep B8: nT8_swz[j][...] = fp8(norm[c][j]) with the 4 16-B chunks of each
// 64-B K-tile group permuted by chunk ^ ((j>>1)&3) (both-sides swizzle src).
// ---------------------------------------------------------------------------
__global__ void prep_nT8(const float* __restrict__ nrm, uint8_t* __restrict__ nT8) {
  __shared__ float tile[64][65];
  const int jb = blockIdx.x & 15;
  const int cb = blockIdx.x >> 4;
  const int t  = threadIdx.x;
  const int r  = t >> 4;
  const int q  = t & 15;
#pragma unroll
  for (int i = 0; i < 4; ++i) {
    int row = r + i * 16;
    f32x4 v = *(const f32x4*)(nrm + (size_t)(cb * 64 + row) * Cc + jb * 64 + q * 4);
#pragma unroll
    for (int s = 0; s < 4; ++s) tile[row][q * 4 + s] = v[s];
  }
  __syncthreads();
#pragma unroll
  for (int i = 0; i < 4; ++i) {
    int j = r + i * 16;                  // row within jb tile; global J = jb*64+j
    u8x4 hs;
#pragma unroll
    for (int s = 0; s < 4; ++s) hs[s] = f2fp8(tile[q * 4 + s][j]);
    int sw  = (j >> 1) & 3;
    int col = cb * 64 + (((q >> 2) ^ sw) * 16) + (q & 3) * 4;
    *(u8x4*)(nT8 + (size_t)(jb * 64 + j) * Cc + col) = hs;
  }
}

// ---------------------------------------------------------------------------
// Prep B (bf16, smallest-ws fused fallback only)
// ---------------------------------------------------------------------------
__global__ void prep_nT(const float* __restrict__ nrm, uint16_t* __restrict__ nT) {
  __shared__ float tile[64][65];
  const int jb = blockIdx.x & 15;
  const int cb = blockIdx.x >> 4;
  const int t  = threadIdx.x;
  const int r  = t >> 4;
  const int q  = t & 15;
#pragma unroll
  for (int i = 0; i < 4; ++i) {
    int row = r + i * 16;
    f32x4 v = *(const f32x4*)(nrm + (size_t)(cb * 64 + row) * Cc + jb * 64 + q * 4);
#pragma unroll
    for (int s = 0; s < 4; ++s) tile[row][q * 4 + s] = v[s];
  }
  __syncthreads();
#pragma unroll
  for (int i = 0; i < 4; ++i) {
    int j = r + i * 16;
    u16x4 hs;
#pragma unroll
    for (int s = 0; s < 4; ++s) hs[s] = f2bf(tile[q * 4 + s][j]);
    *(u16x4*)(nT + (size_t)(jb * 64 + j) * Cc + cb * 64 + q * 4) = hs;
  }
}

// ---------------------------------------------------------------------------
// kexp2: one block per 128-row stripe; colb-loop INSIDE (x read once).
// GEMM1 in bf16 (proven). P stored fp8 e4m3 in the swizzled chunk layout.
// ---------------------------------------------------------------------------
__global__ __launch_bounds__(512, 2) void kexp2(
    const float* __restrict__ x, const float* __restrict__ gam,
    const uint16_t* __restrict__ cenb, const float* __restrict__ c2g,
    uint8_t* __restrict__ P, int row0) {
  extern __shared__ char smem[];
  char*    xB   = smem;                           // [128] rows x 16 chunks, swz
  char*    cB0  = smem + 32768;
  char*    cB1  = smem + 65536;
  uint8_t* pbuf = (uint8_t*)(smem + 98304);       // [128][144] u8
  float*   x2s  = (float*)(smem + 98304 + 128 * 144); // [128]

  const int tid  = threadIdx.x;
  const int lane = tid & 63;
  const int wid  = tid >> 6;     // 0..7
  const int wr   = wid >> 2;     // 0..1 : 64-row half
  const int wn   = wid & 3;      // 0..3 : 32-col quarter
  const int l15  = lane & 15;
  const int l4   = lane >> 4;
  const int mb   = blockIdx.x;

  auto stage_c = [&](char* db, int ct) {
#pragma unroll
    for (int i = 0; i < 4; ++i) {
      int ch = tid + i * 512;    // 2048 chunks of 16B
      int r  = ch >> 4;
      int c  = ch & 15;
      gload16(cenb + (size_t)(ct * 128 + r) * Dk + ((c ^ (r & 7)) * 8),
              db + ch * 16);
    }
  };
  stage_c(cB0, 0);  // prologue: tile 0 in flight under the x staging below

  // ---- stage x (f32 -> bf16, swizzled) + x2 row sums ----
  const float* xblk = x + (size_t)(row0 + mb * 128) * Dk;
#pragma unroll
  for (int it = 0; it < 4; ++it) {
    int ch = tid + it * 512;
    int r  = ch >> 4;
    int cc = ch & 15;
    const float* src = xblk + r * Dk + cc * 8;
    f32x4 v0 = __builtin_nontemporal_load((const f32x4*)src);
    f32x4 v1 = __builtin_nontemporal_load((const f32x4*)(src + 4));
    u16x8 hh;
    float ss = 0.f;
#pragma unroll
    for (int i = 0; i < 4; ++i) {
      hh[i]     = f2bf(v0[i]); ss += v0[i] * v0[i];
      hh[i + 4] = f2bf(v1[i]); ss += v1[i] * v1[i];
    }
    *(u16x8*)(xB + r * 256 + ((cc ^ (r & 7)) * 16)) = hh;
    ss += __shfl_xor(ss, 1);
    ss += __shfl_xor(ss, 2);
    ss += __shfl_xor(ss, 4);
    ss += __shfl_xor(ss, 8);
    if ((tid & 15) == 0) x2s[r] = ss;
  }

  const float ngam = -gam[0];

  for (int ct = 0; ct < 8; ++ct) {
    char* cC = (ct & 1) ? cB1 : cB0;
    char* cN = (ct & 1) ? cB0 : cB1;
    if (ct < 7) stage_c(cN, ct + 1);
    if (ct == 0 || ct == 7) asm volatile("s_waitcnt vmcnt(4)" ::: "memory");
    else                    asm volatile("s_waitcnt vmcnt(8)" ::: "memory");
    __builtin_amdgcn_s_barrier();

    f32x4 cr[4][2];
#pragma unroll
    for (int m = 0; m < 4; ++m)
#pragma unroll
      for (int n = 0; n < 2; ++n) cr[m][n] = f32x4{0.f, 0.f, 0.f, 0.f};

#pragma unroll
    for (int kk = 0; kk < 4; ++kk) {
      bf16x8 aF[4], bF[2];
#pragma unroll
      for (int m = 0; m < 4; ++m) {
        int row = wr * 64 + m * 16 + l15;
        aF[m] = *(const bf16x8*)(xB + row * 256 +
                                 (((kk * 4 + l4) ^ (row & 7)) * 16));
      }
#pragma unroll
      for (int n = 0; n < 2; ++n) {
        int col = wn * 32 + n * 16 + l15;
        bF[n] = *(const bf16x8*)(cC + col * 256 +
                                 (((kk * 4 + l4) ^ (col & 7)) * 16));
      }
#pragma unroll
      for (int m = 0; m < 4; ++m)
#pragma unroll
        for (int n = 0; n < 2; ++n) cr[m][n] = mfma_bf16(aF[m], bF[n], cr[m][n]);
    }

    float c2v[2];
#pragma unroll
    for (int n = 0; n < 2; ++n) c2v[n] = c2g[ct * 128 + wn * 32 + n * 16 + l15];
#pragma unroll
    for (int m = 0; m < 4; ++m) {
#pragma unroll
      for (int n = 0; n < 2; ++n) {
#pragma unroll
        for (int rr = 0; rr < 4; ++rr) {
          int row = wr * 64 + m * 16 + l4 * 4 + rr;
          float s = fmaxf(fmaf(-2.f, cr[m][n][rr], x2s[row] + c2v[n]), 0.f);
          pbuf[row * 144 + wn * 32 + n * 16 + l15] = f2fp8(__expf(ngam * s));
        }
      }
    }
    __builtin_amdgcn_s_barrier();
    // coalesced copy pbuf -> P_swz: permute 16-B chunks within each 64-B group
#pragma unroll
    for (int it = 0; it < 2; ++it) {
      int ch = tid + it * 512;
      int r  = ch >> 3;
      int c  = ch & 7;
      int sw = (r >> 1) & 3;
      int dc = (c & 4) | ((c & 3) ^ sw);
      *(u32x4*)(P + (size_t)(mb * 128 + r) * Cc + ct * 128 + dc * 16) =
          *(const u32x4*)(pbuf + r * 144 + c * 16);
    }
  }
}

// ---------------------------------------------------------------------------
// g2f8 v6 (persistent-A row stripe): out[128 x 1024] per block.
// TRAFFIC FIX: the block's whole P stripe (128 KB fp8) is staged into LDS
// ONCE (fully linear gload_lds copy), then reused across all 4 N-quadrants
// -> P is read exactly 1x total (was 4x) and nT8 (1 MB, L2-resident/XCD)
// is the only per-K-tile staging (2 loads/thread, double-buffered 2x16 KB).
// Fragment reads keep the pre-swizzled chunk layout (conflict-free).
// LDS = 160 KB; acc[2][2]=64 VGPR.
// ---------------------------------------------------------------------------
__global__ __launch_bounds__(512, 2) void g2f8(
    const uint8_t* __restrict__ P, const uint8_t* __restrict__ nT8,
    float* __restrict__ out, int row0) {
  extern __shared__ char smem[];
  char* aS = smem;                 // [128][1024] A stripe (P_swz content)
  char* b0 = smem + 131072;        // [256][64]
  char* b1 = smem + 147456;

  const int tid  = threadIdx.x;
  const int lane = tid & 63;
  const int wid  = tid >> 6;      // 0..7
  const int wm   = wid >> 2;      // 0..1  (64-row half)
  const int wn   = wid & 3;       // 0..3  (64-col quarter within quadrant)
  const int l31  = lane & 31;
  const int lh   = lane >> 5;     // 0..1
  const int mb   = blockIdx.x;

  const uint8_t* Abase = P + (size_t)mb * 128 * Cc;

  auto stageB = [&](char* db, int nb, int k0) {
#pragma unroll
    for (int i = 0; i < 2; ++i) {
      int ch = tid + i * 512;
      int r  = ch >> 2, c = ch & 3;
      gload16(nT8 + (size_t)(nb * 256 + r) * Cc + k0 + c * 16, db + ch * 16);
    }
  };

  // fragment read offsets (loop-invariant), swizzled chunk addressing
  int offA0[2][2], offB[2][2];
#pragma unroll
  for (int m = 0; m < 2; ++m) {
    int row = wm * 64 + m * 32 + l31;   // 0..127
    int s = (row >> 1) & 3;
    offA0[m][0] = row * 1024 + ((2 * lh) ^ s) * 16;
    offA0[m][1] = row * 1024 + ((2 * lh + 1) ^ s) * 16;
  }
#pragma unroll
  for (int n = 0; n < 2; ++n) {
    int row = wn * 64 + n * 32 + l31;   // 0..255
    int s = (row >> 1) & 3;
    offB[n][0] = row * 64 + ((2 * lh) ^ s) * 16;
    offB[n][1] = row * 64 + ((2 * lh + 1) ^ s) * 16;
  }

  f32x16 acc[2][2];
#pragma unroll
  for (int m = 0; m < 2; ++m)
#pragma unroll
    for (int n = 0; n < 2; ++n)
#pragma unroll
      for (int r = 0; r < 16; ++r) acc[m][n][r] = 0.f;

  // prologue: A stripe (16 linear chunks/thread) + B(q0,t0) + B(q0,t1)
#pragma unroll
  for (int i = 0; i < 16; ++i) {
    int ch = tid + i * 512;            // 8192 chunks of 16B
    gload16(Abase + ch * 16, aS + ch * 16);
  }
  stageB(b0, 0, 0);
  stageB(b1, 0, 64);
  asm volatile("s_waitcnt vmcnt(0)" ::: "memory");
  __builtin_amdgcn_s_barrier();

  for (int nb = 0; nb < 4; ++nb) {
    if (nb > 0) {
      stageB(b0, nb, 0);
      stageB(b1, nb, 64);
    }
    for (int kt = 0; kt < 16; ++kt) {
      char* bC = (kt & 1) ? b1 : b0;
      // B(kt) landed; newest 2 loads (B(kt+1)) may stay in flight
      if (kt >= 14) asm volatile("s_waitcnt vmcnt(0)" ::: "memory");
      else          asm volatile("s_waitcnt vmcnt(2)" ::: "memory");
      __builtin_amdgcn_s_barrier();                 // BARRIER1: bC valid

      i32x8 bF[2];
#pragma unroll
      for (int n = 0; n < 2; ++n) {
        i32x4 lo = *(const i32x4*)(bC + offB[n][0]);
        i32x4 hi = *(const i32x4*)(bC + offB[n][1]);
        bF[n] = __builtin_shufflevector(lo, hi, 0, 1, 2, 3, 4, 5, 6, 7);
      }
      __builtin_amdgcn_s_setprio(1);
#pragma unroll
      for (int m = 0; m < 2; ++m) {
        i32x4 lo = *(const i32x4*)(aS + offA0[m][0] + kt * 64);
        i32x4 hi = *(const i32x4*)(aS + offA0[m][1] + kt * 64);
        i32x8 aF = __builtin_shufflevector(lo, hi, 0, 1, 2, 3, 4, 5, 6, 7);
        acc[m][0] = __builtin_amdgcn_mfma_scale_f32_32x32x64_f8f6f4(
            aF, bF[0], acc[m][0], 0, 0, 0, 127, 0, 127);
        acc[m][1] = __builtin_amdgcn_mfma_scale_f32_32x32x64_f8f6f4(
            aF, bF[1], acc[m][1], 0, 0, 0, 127, 0, 127);
      }
      __builtin_amdgcn_s_setprio(0);
      __builtin_amdgcn_s_barrier();                 // BARRIER2: bC free
      if (kt + 2 < 16) stageB(bC, nb, (kt + 2) * 64);
    }

    // ---- quadrant epilogue: bounce via B area ([32][256] f32 = 32 KB) ----
    float* obuf = (float*)(smem + 131072);
#pragma unroll
    for (int h = 0; h < 4; ++h) {
      __syncthreads();
      if (wm == (h >> 1)) {
        const int m = h & 1;
#pragma unroll
        for (int n = 0; n < 2; ++n) {
#pragma unroll
          for (int r = 0; r < 16; ++r) {
            int rin = (r & 3) + 8 * (r >> 2) + 4 * lh;   // 0..31
            obuf[rin * 256 + wn * 64 + n * 32 + l31] = acc[m][n][r];
          }
        }
      }
      __syncthreads();
#pragma unroll
      for (int i = 0; i < 4; ++i) {
        int ch = tid + i * 512;    // 2048 chunks of 16B
        int rL = ch >> 6;          // 0..31
        int c4 = ch & 63;
        *(f32x4*)(out + (size_t)(row0 + mb * 128 + h * 32 + rL) * Cc +
                  nb * 256 + c4 * 4) = *(const f32x4*)(obuf + rL * 256 + c4 * 4);
      }
    }
    __syncthreads();   // bounce reads done before next quadrant's stageB
#pragma unroll
    for (int m = 0; m < 2; ++m)
#pragma unroll
      for (int n = 0; n < 2; ++n)
#pragma unroll
        for (int r = 0; r < 16; ++r) acc[m][n][r] = 0.f;
  }
}

// ---------------------------------------------------------------------------
// Fused fallback (R5) — only used when ws is too small for the split path.
// ---------------------------------------------------------------------------
template <int USE_NT>
__global__ __launch_bounds__(512, 4) void nyst_main(
    const float* __restrict__ x, const float* __restrict__ cen,
    const float* __restrict__ gam, const float* __restrict__ nrm,
    const uint16_t* __restrict__ cenb, const float* __restrict__ c2g,
    const uint16_t* __restrict__ nT, float* __restrict__ out) {
  extern __shared__ char smem[];
  char*  xB  = smem;
  char*  pB  = smem + XBYTES;
  float* x2s = (float*)(smem + XBYTES + PBYTES);
  float* c2s = (float*)(smem + LDS_MAIN);

  const int tid  = threadIdx.x;
  const int lane = tid & 63;
  const int wid  = tid >> 6;
  const int wr   = wid >> 2;
  const int wc   = wid & 3;
  const int xcd  = blockIdx.x & 7;
  const int bi   = blockIdx.x >> 3;
  const int colb = xcd >> 1;
  const int rowb = (bi << 1) | (xcd & 1);
  const int l15  = lane & 15;
  const int l4   = lane >> 4;

  const float* xblk = x + (size_t)rowb * BMf * Dk;

#pragma unroll
  for (int it = 0; it < 2; ++it) {
    int ch = tid + it * 512;
    int r  = ch >> 4;
    int cc = ch & 15;
    const float* src = xblk + r * Dk + cc * 8;
    f32x4 v0 = __builtin_nontemporal_load((const f32x4*)src);
    f32x4 v1 = __builtin_nontemporal_load((const f32x4*)(src + 4));
    u16x8 hh;
    float ss = 0.f;
#pragma unroll
    for (int i = 0; i < 4; ++i) {
      hh[i]     = f2bf(v0[i]); ss += v0[i] * v0[i];
      hh[i + 4] = f2bf(v1[i]); ss += v1[i] * v1[i];
    }
    int off = (r * 256 + cc * 16) ^ ((r & 7) << 4);
    *(u16x8*)(xB + off) = hh;
    ss += __shfl_xor(ss, 1);
    ss += __shfl_xor(ss, 2);
    ss += __shfl_xor(ss, 4);
    ss += __shfl_xor(ss, 8);
    if ((tid & 15) == 0) x2s[r] = ss;
  }
  if (!USE_NT) {
#pragma unroll
    for (int rr = 0; rr < 2; ++rr) {
      int r = tid + rr * 512;
      const float* src = cen + (size_t)r * Dk;
      float ss = 0.f;
      for (int k = 0; k < Dk / 4; ++k) {
        f32x4 v = *(const f32x4*)(src + 4 * k);
        ss += v[0] * v[0] + v[1] * v[1] + v[2] * v[2] + v[3] * v[3];
      }
      c2s[r] = ss;
    }
  }
  __syncthreads();

  const float ngam = -gam[0];
  f32x4 zero4 = {0.f, 0.f, 0.f, 0.f};
  f32x4 acc[2][4];
#pragma unroll
  for (int m = 0; m < 2; ++m)
#pragma unroll
    for (int n = 0; n < 4; ++n) acc[m][n] = zero4;

  for (int c0 = 0; c0 < Cc; c0 += KBf) {
    f32x4 cr[2][2];
#pragma unroll
    for (int g = 0; g < 2; ++g)
#pragma unroll
      for (int m = 0; m < 2; ++m) cr[g][m] = zero4;

#pragma unroll
    for (int kk = 0; kk < 4; ++kk) {
      bf16x8 b0, b1;
      if (USE_NT) {
        int c0col = c0 + 16 * wc + l15;
        b0 = *(const bf16x8*)(cenb + (size_t)c0col * Dk + kk * 32 + l4 * 8);
        b1 = *(const bf16x8*)(cenb + (size_t)(c0col + 64) * Dk + kk * 32 + l4 * 8);
      } else {
#pragma unroll
        for (int g = 0; g < 2; ++g) {
          int ccol = c0 + g * 64 + 16 * wc + l15;
          const float* cb_ = cen + (size_t)ccol * Dk + kk * 32 + l4 * 8;
          f32x4 v0 = *(const f32x4*)cb_;
          f32x4 v1 = *(const f32x4*)(cb_ + 4);
          u16x8 tt;
#pragma unroll
          for (int i = 0; i < 4; ++i) { tt[i] = f2bf(v0[i]); tt[i + 4] = f2bf(v1[i]); }
          if (g == 0) b0 = __builtin_bit_cast(bf16x8, tt);
          else        b1 = __builtin_bit_cast(bf16x8, tt);
        }
      }
#pragma unroll
      for (int m = 0; m < 2; ++m) {
        int row = 32 * wr + 16 * m + l15;
        int off = (row * 256 + kk * 64 + l4 * 16) ^ ((row & 7) << 4);
        bf16x8 a = *(const bf16x8*)(xB + off);
        cr[0][m] = mfma_bf16(a, b0, cr[0][m]);
        cr[1][m] = mfma_bf16(a, b1, cr[1][m]);
      }
    }

    __syncthreads();
#pragma unroll
    for (int g = 0; g < 2; ++g) {
      int ccol = c0 + g * 64 + 16 * wc + l15;
      float c2v = USE_NT ? c2g[ccol] : c2s[ccol];
#pragma unroll
      for (int m = 0; m < 2; ++m) {
#pragma unroll
        for (int r = 0; r < 4; ++r) {
          int row = 32 * wr + 16 * m + l4 * 4 + r;
          float s = fmaxf(fmaf(-2.f, cr[g][m][r], x2s[row] + c2v), 0.f);
          float p = __expf(ngam * s);
          int off = (row * 256 + (g * 64 + 16 * wc + l15) * 2) ^ ((row & 7) << 4);
          *(uint16_t*)(pB + off) = f2bf(p);
        }
      }
    }
    __syncthreads();

#pragma unroll
    for (int kk = 0; kk < 4; ++kk) {
      bf16x8 pa[2];
#pragma unroll
      for (int m = 0; m < 2; ++m) {
        int row = 32 * wr + 16 * m + l15;
        int off = (row * 256 + kk * 64 + l4 * 16) ^ ((row & 7) << 4);
        pa[m] = *(const bf16x8*)(pB + off);
      }
      int krow = c0 + kk * 32 + l4 * 8;
#pragma unroll
      for (int n = 0; n < 4; ++n) {
        int j = colb * BNf + wc * 64 + 16 * n + l15;
        bf16x8 bm;
        if (USE_NT) {
          bm = *(const bf16x8*)(nT + (size_t)j * Cc + krow);
        } else {
          u16x8 tt;
#pragma unroll
          for (int i = 0; i < 8; ++i) tt[i] = f2bf(nrm[(size_t)(krow + i) * Cc + j]);
          bm = __builtin_bit_cast(bf16x8, tt);
        }
        acc[0][n] = mfma_bf16(pa[0], bm, acc[0][n]);
        acc[1][n] = mfma_bf16(pa[1], bm, acc[1][n]);
      }
    }
  }

  float* outBuf = (float*)smem;
  const int orow0 = rowb * BMf;
#pragma unroll
  for (int h = 0; h < 2; ++h) {
    __syncthreads();
    if (wr == h) {
#pragma unroll
      for (int m = 0; m < 2; ++m) {
#pragma unroll
        for (int n = 0; n < 4; ++n) {
#pragma unroll
          for (int r = 0; r < 4; ++r) {
            int rL = 16 * m + l4 * 4 + r;
            outBuf[rL * 256 + wc * 64 + 16 * n + l15] = acc[m][n][r];
          }
        }
      }
    }
    __syncthreads();
#pragma unroll
    for (int i = 0; i < 4; ++i) {
      int ch = tid + 512 * i;
      int rL = ch >> 6;
      int c4 = ch & 63;
      f32x4 v = *(const f32x4*)(outBuf + rL * 256 + c4 * 4);
      *(f32x4*)(out + (size_t)(orow0 + 32 * h + rL) * Cc + colb * BNf + c4 * 4) = v;
    }
  }
}

// ---------------------------------------------------------------------------
extern "C" void kernel_launch(void* const* d_in, const int* in_sizes, int n_in,
                              void* d_out, int out_size, void* d_ws, size_t ws_size,
                              hipStream_t stream) {
  const float* x   = (const float*)d_in[0];  // [131072,128]
  const float* cen = (const float*)d_in[1];  // [1024,128]
  const float* gam = (const float*)d_in[2];  // [1]
  const float* nrm = (const float*)d_in[3];  // [1024,1024]
  float* out = (float*)d_out;

  const size_t cenbB = (size_t)Cc * Dk * 2;            // 256 KB
  const size_t c2B   = (size_t)Cc * 4;                 // 4 KB
  const size_t nT8B  = (size_t)Cc * Cc;                // 1 MB (fp8)
  const size_t nTB   = (size_t)Cc * Cc * 2;            // 2 MB (bf16 fallback)
  const size_t pFull = (size_t)Nrows * Cc;             // 134 MB (fp8)
  const size_t pChB  = (size_t)CH * Cc;                // 16.8 MB (fp8)

  if (ws_size >= cenbB + c2B + nT8B + pFull) {
    uint16_t* cenb = (uint16_t*)d_ws;
    float*    c2   = (float*)((char*)d_ws + cenbB);
    uint8_t*  nT8  = (uint8_t*)((char*)d_ws + cenbB + c2B);
    uint8_t*  Pws  = (uint8_t*)((char*)d_ws + cenbB + c2B + nT8B);
    prep_cen<<<64, 256, 0, stream>>>(cen, cenb, c2);
    prep_nT8<<<256, 256, 0, stream>>>(nrm, nT8);
    kexp2<<<Nrows / 128, 512, KEXP2_LDS, stream>>>(x, gam, cenb, c2, Pws, 0);
    g2f8<<<Nrows / 128, 512, G2F8_LDS, stream>>>(Pws, nT8, out, 0);
  } else if (ws_size >= cenbB + c2B + nT8B + pChB) {
    uint16_t* cenb = (uint16_t*)d_ws;
    float*    c2   = (float*)((char*)d_ws + cenbB);
    uint8_t*  nT8  = (uint8_t*)((char*)d_ws + cenbB + c2B);
    uint8_t*  Pws  = (uint8_t*)((char*)d_ws + cenbB + c2B + nT8B);
    prep_cen<<<64, 256, 0, stream>>>(cen, cenb, c2);
    prep_nT8<<<256, 256, 0, stream>>>(nrm, nT8);
    for (int c = 0; c < NCHUNK; ++c) {
      kexp2<<<CH / 128, 512, KEXP2_LDS, stream>>>(x, gam, cenb, c2, Pws, c * CH);
      g2f8<<<CH / 128, 512, G2F8_LDS, stream>>>(Pws, nT8, out, c * CH);
    }
  } else if (ws_size >= cenbB + c2B + nTB) {
    uint16_t* cenb = (uint16_t*)d_ws;
    float*    c2   = (float*)((char*)d_ws + cenbB);
    uint16_t* nT   = (uint16_t*)((char*)d_ws + cenbB + c2B);
    prep_cen<<<64, 256, 0, stream>>>(cen, cenb, c2);
    prep_nT<<<256, 256, 0, stream>>>(nrm, nT);
    nyst_main<1><<<(Nrows / BMf) * (Cc / BNf), 512, LDS_MAIN, stream>>>(
        x, cen, gam, nrm, cenb, c2, nT, out);
  } else {
    nyst_main<0><<<(Nrows / BMf) * (Cc / BNf), 512, LDS_FB, stream>>>(
        x, cen, gam, nrm, nullptr, nullptr, nullptr, out);
  }
}

// Round 19
// 320.390 us; speedup vs baseline: 2.4651x; 2.4651x over previous
//
#include <hip/hip_runtime.h>
#include <hip/hip_fp8.h>
#include <stdint.h>

typedef float    f32x4  __attribute__((ext_vector_type(4)));
typedef float    f32x16 __attribute__((ext_vector_type(16)));
typedef int      i32x4  __attribute__((ext_vector_type(4)));
typedef int      i32x8  __attribute__((ext_vector_type(8)));
typedef __bf16   bf16x8 __attribute__((ext_vector_type(8)));
typedef uint16_t u16x8  __attribute__((ext_vector_type(8)));
typedef uint16_t u16x4  __attribute__((ext_vector_type(4)));
typedef uint8_t  u8x4   __attribute__((ext_vector_type(4)));
typedef uint32_t u32x4  __attribute__((ext_vector_type(4)));

static __device__ __forceinline__ f32x4 mfma_bf16(bf16x8 a, bf16x8 b, f32x4 c) {
  return __builtin_amdgcn_mfma_f32_16x16x32_bf16(a, b, c, 0, 0, 0);
}
// fp32 -> bf16 round-to-nearest-even
static __device__ __forceinline__ uint16_t f2bf(float f) {
  uint32_t u = __builtin_bit_cast(uint32_t, f);
  u += 0x7fffu + ((u >> 16) & 1u);
  return (uint16_t)(u >> 16);
}
// fp32 -> fp8 OCP e4m3fn
static __device__ __forceinline__ uint8_t f2fp8(float f) {
  __hip_fp8_e4m3 v(f);
  return v.__x;
}
// async global->LDS, 16B per lane (gfx950). dest must be linear-in-lane.
static __device__ __forceinline__ void gload16(const void* src, void* lds) {
  __builtin_amdgcn_global_load_lds(
      (const __attribute__((address_space(1))) void*)src,
      (__attribute__((address_space(3))) void*)lds, 16, 0, 0);
}

constexpr int Nrows = 131072;
constexpr int Dk    = 128;
constexpr int Cc    = 1024;
constexpr int CH     = 16384;          // rows per chunk (mid-ws fallback)
constexpr int NCHUNK = Nrows / CH;     // 8
// fused fallback (R5) geometry
constexpr int BMf   = 64;
constexpr int BNf   = 256;
constexpr int KBf   = 128;
constexpr int XBYTES = BMf * Dk * 2;
constexpr int PBYTES = BMf * KBf * 2;
constexpr int LDS_MAIN = XBYTES + PBYTES + BMf * 4;
constexpr int LDS_FB   = LDS_MAIN + Cc * 4;
constexpr int KEXP2_LDS = 32768 * 3 + 128 * 144 + 512;   // 116864

// ---------------------------------------------------------------------------
// Prep A: centers -> bf16 [C][D], and c2[C]
// ---------------------------------------------------------------------------
__global__ void prep_cen(const float* __restrict__ cen,
                         uint16_t* __restrict__ cenb,
                         float* __restrict__ c2) {
  const int t = threadIdx.x;
  const int row = blockIdx.x * 16 + (t >> 4);
  const int q = t & 15;
  const float* src = cen + (size_t)row * Dk + q * 8;
  f32x4 v0 = *(const f32x4*)src;
  f32x4 v1 = *(const f32x4*)(src + 4);
  u16x8 h;
  float ss = 0.f;
#pragma unroll
  for (int i = 0; i < 4; ++i) {
    h[i]     = f2bf(v0[i]); ss += v0[i] * v0[i];
    h[i + 4] = f2bf(v1[i]); ss += v1[i] * v1[i];
  }
  *(u16x8*)(cenb + (size_t)row * Dk + q * 8) = h;
  ss += __shfl_xor(ss, 1);
  ss += __shfl_xor(ss, 2);
  ss += __shfl_xor(ss, 4);
  ss += __shfl_xor(ss, 8);
  if (q == 0) c2[row] = ss;
}

// ---------------------------------------------------------------------------
// Prep B8: nT8_swz[j][...] = fp8(norm[c][j]) with the 4 16-B chunks of each
// 64-B K-tile group permuted by chunk ^ ((j>>1)&3) (both-sides swizzle src).
// ---------------------------------------------------------------------------
__global__ void prep_nT8(const float* __restrict__ nrm, uint8_t* __restrict__ nT8) {
  __shared__ float tile[64][65];
  const int jb = blockIdx.x & 15;
  const int cb = blockIdx.x >> 4;
  const int t  = threadIdx.x;
  const int r  = t >> 4;
  const int q  = t & 15;
#pragma unroll
  for (int i = 0; i < 4; ++i) {
    int row = r + i * 16;
    f32x4 v = *(const f32x4*)(nrm + (size_t)(cb * 64 + row) * Cc + jb * 64 + q * 4);
#pragma unroll
    for (int s = 0; s < 4; ++s) tile[row][q * 4 + s] = v[s];
  }
  __syncthreads();
#pragma unroll
  for (int i = 0; i < 4; ++i) {
    int j = r + i * 16;                  // row within jb tile; global J = jb*64+j
    u8x4 hs;
#pragma unroll
    for (int s = 0; s < 4; ++s) hs[s] = f2fp8(tile[q * 4 + s][j]);
    int sw  = (j >> 1) & 3;
    int col = cb * 64 + (((q >> 2) ^ sw) * 16) + (q & 3) * 4;
    *(u8x4*)(nT8 + (size_t)(jb * 64 + j) * Cc + col) = hs;
  }
}

// ---------------------------------------------------------------------------
// Prep B (bf16, smallest-ws fused fallback only)
// ---------------------------------------------------------------------------
__global__ void prep_nT(const float* __restrict__ nrm, uint16_t* __restrict__ nT) {
  __shared__ float tile[64][65];
  const int jb = blockIdx.x & 15;
  const int cb = blockIdx.x >> 4;
  const int t  = threadIdx.x;
  const int r  = t >> 4;
  const int q  = t & 15;
#pragma unroll
  for (int i = 0; i < 4; ++i) {
    int row = r + i * 16;
    f32x4 v = *(const f32x4*)(nrm + (size_t)(cb * 64 + row) * Cc + jb * 64 + q * 4);
#pragma unroll
    for (int s = 0; s < 4; ++s) tile[row][q * 4 + s] = v[s];
  }
  __syncthreads();
#pragma unroll
  for (int i = 0; i < 4; ++i) {
    int j = r + i * 16;
    u16x4 hs;
#pragma unroll
    for (int s = 0; s < 4; ++s) hs[s] = f2bf(tile[q * 4 + s][j]);
    *(u16x4*)(nT + (size_t)(jb * 64 + j) * Cc + cb * 64 + q * 4) = hs;
  }
}

// ---------------------------------------------------------------------------
// kexp2: one block per 128-row stripe; colb-loop INSIDE (x read once).
// GEMM1 in bf16 (proven). P stored fp8 e4m3 in the swizzled chunk layout.
// ---------------------------------------------------------------------------
__global__ __launch_bounds__(512, 2) void kexp2(
    const float* __restrict__ x, const float* __restrict__ gam,
    const uint16_t* __restrict__ cenb, const float* __restrict__ c2g,
    uint8_t* __restrict__ P, int row0) {
  extern __shared__ char smem[];
  char*    xB   = smem;                           // [128] rows x 16 chunks, swz
  char*    cB0  = smem + 32768;
  char*    cB1  = smem + 65536;
  uint8_t* pbuf = (uint8_t*)(smem + 98304);       // [128][144] u8
  float*   x2s  = (float*)(smem + 98304 + 128 * 144); // [128]

  const int tid  = threadIdx.x;
  const int lane = tid & 63;
  const int wid  = tid >> 6;     // 0..7
  const int wr   = wid >> 2;     // 0..1 : 64-row half
  const int wn   = wid & 3;      // 0..3 : 32-col quarter
  const int l15  = lane & 15;
  const int l4   = lane >> 4;
  const int mb   = blockIdx.x;

  auto stage_c = [&](char* db, int ct) {
#pragma unroll
    for (int i = 0; i < 4; ++i) {
      int ch = tid + i * 512;    // 2048 chunks of 16B
      int r  = ch >> 4;
      int c  = ch & 15;
      gload16(cenb + (size_t)(ct * 128 + r) * Dk + ((c ^ (r & 7)) * 8),
              db + ch * 16);
    }
  };
  stage_c(cB0, 0);  // prologue: tile 0 in flight under the x staging below

  // ---- stage x (f32 -> bf16, swizzled) + x2 row sums ----
  const float* xblk = x + (size_t)(row0 + mb * 128) * Dk;
#pragma unroll
  for (int it = 0; it < 4; ++it) {
    int ch = tid + it * 512;
    int r  = ch >> 4;
    int cc = ch & 15;
    const float* src = xblk + r * Dk + cc * 8;
    f32x4 v0 = __builtin_nontemporal_load((const f32x4*)src);
    f32x4 v1 = __builtin_nontemporal_load((const f32x4*)(src + 4));
    u16x8 hh;
    float ss = 0.f;
#pragma unroll
    for (int i = 0; i < 4; ++i) {
      hh[i]     = f2bf(v0[i]); ss += v0[i] * v0[i];
      hh[i + 4] = f2bf(v1[i]); ss += v1[i] * v1[i];
    }
    *(u16x8*)(xB + r * 256 + ((cc ^ (r & 7)) * 16)) = hh;
    ss += __shfl_xor(ss, 1);
    ss += __shfl_xor(ss, 2);
    ss += __shfl_xor(ss, 4);
    ss += __shfl_xor(ss, 8);
    if ((tid & 15) == 0) x2s[r] = ss;
  }

  const float ngam = -gam[0];

  for (int ct = 0; ct < 8; ++ct) {
    char* cC = (ct & 1) ? cB1 : cB0;
    char* cN = (ct & 1) ? cB0 : cB1;
    if (ct < 7) stage_c(cN, ct + 1);
    if (ct == 0 || ct == 7) asm volatile("s_waitcnt vmcnt(4)" ::: "memory");
    else                    asm volatile("s_waitcnt vmcnt(8)" ::: "memory");
    __builtin_amdgcn_s_barrier();

    f32x4 cr[4][2];
#pragma unroll
    for (int m = 0; m < 4; ++m)
#pragma unroll
      for (int n = 0; n < 2; ++n) cr[m][n] = f32x4{0.f, 0.f, 0.f, 0.f};

#pragma unroll
    for (int kk = 0; kk < 4; ++kk) {
      bf16x8 aF[4], bF[2];
#pragma unroll
      for (int m = 0; m < 4; ++m) {
        int row = wr * 64 + m * 16 + l15;
        aF[m] = *(const bf16x8*)(xB + row * 256 +
                                 (((kk * 4 + l4) ^ (row & 7)) * 16));
      }
#pragma unroll
      for (int n = 0; n < 2; ++n) {
        int col = wn * 32 + n * 16 + l15;
        bF[n] = *(const bf16x8*)(cC + col * 256 +
                                 (((kk * 4 + l4) ^ (col & 7)) * 16));
      }
#pragma unroll
      for (int m = 0; m < 4; ++m)
#pragma unroll
        for (int n = 0; n < 2; ++n) cr[m][n] = mfma_bf16(aF[m], bF[n], cr[m][n]);
    }

    float c2v[2];
#pragma unroll
    for (int n = 0; n < 2; ++n) c2v[n] = c2g[ct * 128 + wn * 32 + n * 16 + l15];
#pragma unroll
    for (int m = 0; m < 4; ++m) {
#pragma unroll
      for (int n = 0; n < 2; ++n) {
#pragma unroll
        for (int rr = 0; rr < 4; ++rr) {
          int row = wr * 64 + m * 16 + l4 * 4 + rr;
          float s = fmaxf(fmaf(-2.f, cr[m][n][rr], x2s[row] + c2v[n]), 0.f);
          pbuf[row * 144 + wn * 32 + n * 16 + l15] = f2fp8(__expf(ngam * s));
        }
      }
    }
    __builtin_amdgcn_s_barrier();
    // coalesced copy pbuf -> P_swz: permute 16-B chunks within each 64-B group
#pragma unroll
    for (int it = 0; it < 2; ++it) {
      int ch = tid + it * 512;
      int r  = ch >> 3;
      int c  = ch & 7;
      int sw = (r >> 1) & 3;
      int dc = (c & 4) | ((c & 3) ^ sw);
      *(u32x4*)(P + (size_t)(mb * 128 + r) * Cc + ct * 128 + dc * 16) =
          *(const u32x4*)(pbuf + r * 144 + c * 16);
    }
  }
}

// ---------------------------------------------------------------------------
// g2f8 (R16, proven best): out = P_swz(fp8) @ nT8_swz^T (fp8), MX MFMA
// 32x32x64, unit scales. gload_lds staging + minimal-barrier loop; the
// 16-way fragment-read bank conflict is fixed by the PRE-SWIZZLED GLOBAL
// layout (both-sides rule): staging is linear src -> linear LDS dest;
// fragment reads use offset chunk ^ ((row>>1)&3) -> 8 consecutive rows hit
// all 8 bank-quads (4 lanes/quad, throughput-optimal).
// ---------------------------------------------------------------------------
__global__ __launch_bounds__(512, 2) void g2f8(
    const uint8_t* __restrict__ P, const uint8_t* __restrict__ nT8,
    float* __restrict__ out, int row0, int mblocks) {
  extern __shared__ char smem[];
  char* a0 = smem;             // [256] rows x 64B (pre-swizzled content)
  char* b0 = smem + 16384;
  char* a1 = smem + 32768;
  char* b1 = smem + 49152;

  const int tid  = threadIdx.x;
  const int lane = tid & 63;
  const int wid  = tid >> 6;      // 0..7
  const int wm   = wid >> 2;      // 0..1
  const int wn   = wid & 3;       // 0..3
  const int l31  = lane & 31;
  const int lh   = lane >> 5;     // 0..1

  // bijective XCD swizzle (nwg % 8 == 0): nb fastest within an XCD's chunk.
  const int nwg  = mblocks * 4;
  const int cpx  = nwg >> 3;
  const int wgid = (blockIdx.x & 7) * cpx + (blockIdx.x >> 3);
  const int nb   = wgid & 3;
  const int mb   = wgid >> 2;

  const uint8_t* Abase = P + (size_t)mb * 256 * Cc;
  const uint8_t* Bbase = nT8 + (size_t)nb * 256 * Cc;

  // stage one 16 KB tile: 1024 chunks of 16B, 2/thread, linear both sides
  auto stage = [&](const uint8_t* gb, char* db, int k0) {
#pragma unroll
    for (int i = 0; i < 2; ++i) {
      int ch = tid + i * 512;
      int r  = ch >> 2;          // row 0..255 (64 B rows)
      int c  = ch & 3;
      gload16(gb + (size_t)r * Cc + k0 + c * 16, db + ch * 16);
    }
  };

  // fragment read offsets (loop-invariant): swizzled chunk addressing
  int offA[4][2], offB[2][2];
#pragma unroll
  for (int m = 0; m < 4; ++m) {
    int row = wm * 128 + m * 32 + l31;
    int s = (row >> 1) & 3;
    offA[m][0] = row * 64 + ((2 * lh) ^ s) * 16;
    offA[m][1] = row * 64 + ((2 * lh + 1) ^ s) * 16;
  }
#pragma unroll
  for (int n = 0; n < 2; ++n) {
    int row = wn * 64 + n * 32 + l31;
    int s = (row >> 1) & 3;
    offB[n][0] = row * 64 + ((2 * lh) ^ s) * 16;
    offB[n][1] = row * 64 + ((2 * lh + 1) ^ s) * 16;
  }
  auto ldfrag = [&](const char* base, const int (&off)[2]) -> i32x8 {
    i32x4 lo = *(const i32x4*)(base + off[0]);
    i32x4 hi = *(const i32x4*)(base + off[1]);
    return __builtin_shufflevector(lo, hi, 0, 1, 2, 3, 4, 5, 6, 7);
  };

  f32x16 acc[4][2];
#pragma unroll
  for (int m = 0; m < 4; ++m)
#pragma unroll
    for (int n = 0; n < 2; ++n)
#pragma unroll
      for (int r = 0; r < 16; ++r) acc[m][n][r] = 0.f;

  // prologue: B(0), A(0), B(1)
  stage(Bbase, b0, 0);
  stage(Abase, a0, 0);
  stage(Bbase, b1, 64);

  for (int kt = 0; kt < 16; ++kt) {
    const int q = kt & 1;
    char* aC = q ? a1 : a0;
    char* bC = q ? b1 : b0;
    char* aN = q ? a0 : a1;

    // A(kt),B(kt) landed; newest 2 loads (B(kt+1)) may stay in flight
    if (kt == 15) asm volatile("s_waitcnt vmcnt(0)" ::: "memory");
    else          asm volatile("s_waitcnt vmcnt(2)" ::: "memory");
    __builtin_amdgcn_s_barrier();                 // BARRIER1

    if (kt + 1 < 16) stage(Abase, aN, (kt + 1) * 64);

    // consume B(kt) into registers
    i32x8 bF[2];
#pragma unroll
    for (int n = 0; n < 2; ++n) bF[n] = ldfrag(bC, offB[n]);

    {
      i32x8 aF = ldfrag(aC, offA[0]);             // m=0
      __builtin_amdgcn_s_setprio(1);
      acc[0][0] = __builtin_amdgcn_mfma_scale_f32_32x32x64_f8f6f4(
          aF, bF[0], acc[0][0], 0, 0, 0, 127, 0, 127);
      acc[0][1] = __builtin_amdgcn_mfma_scale_f32_32x32x64_f8f6f4(
          aF, bF[1], acc[0][1], 0, 0, 0, 127, 0, 127);
      __builtin_amdgcn_s_setprio(0);
    }
    __builtin_amdgcn_s_barrier();                 // BARRIER2: bC free
    if (kt + 2 < 16) stage(Bbase, bC, (kt + 2) * 64);

    // m = 1..3: straight-line; compiler pipelines A-reads under MFMAs
    __builtin_amdgcn_s_setprio(1);
#pragma unroll
    for (int m = 1; m < 4; ++m) {
      i32x8 aF = ldfrag(aC, offA[m]);
      acc[m][0] = __builtin_amdgcn_mfma_scale_f32_32x32x64_f8f6f4(
          aF, bF[0], acc[m][0], 0, 0, 0, 127, 0, 127);
      acc[m][1] = __builtin_amdgcn_mfma_scale_f32_32x32x64_f8f6f4(
          aF, bF[1], acc[m][1], 0, 0, 0, 127, 0, 127);
    }
    __builtin_amdgcn_s_setprio(0);
  }

  // epilogue: 4 rounds of 64 rows through a [64][256] f32 bounce (64 KB).
  // C/D 32x32 layout: col=lane&31, row=(reg&3)+8*(reg>>2)+4*(lane>>5).
  float* obuf = (float*)smem;
#pragma unroll
  for (int h = 0; h < 4; ++h) {
    __syncthreads();
    if (wm == (h >> 1)) {
      const int mbase = (h & 1) * 2;
#pragma unroll
      for (int ml = 0; ml < 2; ++ml) {
#pragma unroll
        for (int n = 0; n < 2; ++n) {
#pragma unroll
          for (int r = 0; r < 16; ++r) {
            int rin = (r & 3) + 8 * (r >> 2) + 4 * lh;
            obuf[(ml * 32 + rin) * 256 + wn * 64 + n * 32 + l31] =
                acc[mbase + ml][n][r];
          }
        }
      }
    }
    __syncthreads();
#pragma unroll
    for (int i = 0; i < 8; ++i) {
      int ch = tid + i * 512;   // 4096 chunks of 16B
      int rL = ch >> 6;         // 0..63
      int c4 = ch & 63;
      *(f32x4*)(out + (size_t)(row0 + mb * 256 + h * 64 + rL) * Cc +
                nb * 256 + c4 * 4) = *(const f32x4*)(obuf + rL * 256 + c4 * 4);
    }
  }
}

// ---------------------------------------------------------------------------
// Fused fallback (R5) — only used when ws is too small for the split path.
// ---------------------------------------------------------------------------
template <int USE_NT>
__global__ __launch_bounds__(512, 4) void nyst_main(
    const float* __restrict__ x, const float* __restrict__ cen,
    const float* __restrict__ gam, const float* __restrict__ nrm,
    const uint16_t* __restrict__ cenb, const float* __restrict__ c2g,
    const uint16_t* __restrict__ nT, float* __restrict__ out) {
  extern __shared__ char smem[];
  char*  xB  = smem;
  char*  pB  = smem + XBYTES;
  float* x2s = (float*)(smem + XBYTES + PBYTES);
  float* c2s = (float*)(smem + LDS_MAIN);

  const int tid  = threadIdx.x;
  const int lane = tid & 63;
  const int wid  = tid >> 6;
  const int wr   = wid >> 2;
  const int wc   = wid & 3;
  const int xcd  = blockIdx.x & 7;
  const int bi   = blockIdx.x >> 3;
  const int colb = xcd >> 1;
  const int rowb = (bi << 1) | (xcd & 1);
  const int l15  = lane & 15;
  const int l4   = lane >> 4;

  const float* xblk = x + (size_t)rowb * BMf * Dk;

#pragma unroll
  for (int it = 0; it < 2; ++it) {
    int ch = tid + it * 512;
    int r  = ch >> 4;
    int cc = ch & 15;
    const float* src = xblk + r * Dk + cc * 8;
    f32x4 v0 = __builtin_nontemporal_load((const f32x4*)src);
    f32x4 v1 = __builtin_nontemporal_load((const f32x4*)(src + 4));
    u16x8 hh;
    float ss = 0.f;
#pragma unroll
    for (int i = 0; i < 4; ++i) {
      hh[i]     = f2bf(v0[i]); ss += v0[i] * v0[i];
      hh[i + 4] = f2bf(v1[i]); ss += v1[i] * v1[i];
    }
    int off = (r * 256 + cc * 16) ^ ((r & 7) << 4);
    *(u16x8*)(xB + off) = hh;
    ss += __shfl_xor(ss, 1);
    ss += __shfl_xor(ss, 2);
    ss += __shfl_xor(ss, 4);
    ss += __shfl_xor(ss, 8);
    if ((tid & 15) == 0) x2s[r] = ss;
  }
  if (!USE_NT) {
#pragma unroll
    for (int rr = 0; rr < 2; ++rr) {
      int r = tid + rr * 512;
      const float* src = cen + (size_t)r * Dk;
      float ss = 0.f;
      for (int k = 0; k < Dk / 4; ++k) {
        f32x4 v = *(const f32x4*)(src + 4 * k);
        ss += v[0] * v[0] + v[1] * v[1] + v[2] * v[2] + v[3] * v[3];
      }
      c2s[r] = ss;
    }
  }
  __syncthreads();

  const float ngam = -gam[0];
  f32x4 zero4 = {0.f, 0.f, 0.f, 0.f};
  f32x4 acc[2][4];
#pragma unroll
  for (int m = 0; m < 2; ++m)
#pragma unroll
    for (int n = 0; n < 4; ++n) acc[m][n] = zero4;

  for (int c0 = 0; c0 < Cc; c0 += KBf) {
    f32x4 cr[2][2];
#pragma unroll
    for (int g = 0; g < 2; ++g)
#pragma unroll
      for (int m = 0; m < 2; ++m) cr[g][m] = zero4;

#pragma unroll
    for (int kk = 0; kk < 4; ++kk) {
      bf16x8 b0, b1;
      if (USE_NT) {
        int c0col = c0 + 16 * wc + l15;
        b0 = *(const bf16x8*)(cenb + (size_t)c0col * Dk + kk * 32 + l4 * 8);
        b1 = *(const bf16x8*)(cenb + (size_t)(c0col + 64) * Dk + kk * 32 + l4 * 8);
      } else {
#pragma unroll
        for (int g = 0; g < 2; ++g) {
          int ccol = c0 + g * 64 + 16 * wc + l15;
          const float* cb_ = cen + (size_t)ccol * Dk + kk * 32 + l4 * 8;
          f32x4 v0 = *(const f32x4*)cb_;
          f32x4 v1 = *(const f32x4*)(cb_ + 4);
          u16x8 tt;
#pragma unroll
          for (int i = 0; i < 4; ++i) { tt[i] = f2bf(v0[i]); tt[i + 4] = f2bf(v1[i]); }
          if (g == 0) b0 = __builtin_bit_cast(bf16x8, tt);
          else        b1 = __builtin_bit_cast(bf16x8, tt);
        }
      }
#pragma unroll
      for (int m = 0; m < 2; ++m) {
        int row = 32 * wr + 16 * m + l15;
        int off = (row * 256 + kk * 64 + l4 * 16) ^ ((row & 7) << 4);
        bf16x8 a = *(const bf16x8*)(xB + off);
        cr[0][m] = mfma_bf16(a, b0, cr[0][m]);
        cr[1][m] = mfma_bf16(a, b1, cr[1][m]);
      }
    }

    __syncthreads();
#pragma unroll
    for (int g = 0; g < 2; ++g) {
      int ccol = c0 + g * 64 + 16 * wc + l15;
      float c2v = USE_NT ? c2g[ccol] : c2s[ccol];
#pragma unroll
      for (int m = 0; m < 2; ++m) {
#pragma unroll
        for (int r = 0; r < 4; ++r) {
          int row = 32 * wr + 16 * m + l4 * 4 + r;
          float s = fmaxf(fmaf(-2.f, cr[g][m][r], x2s[row] + c2v), 0.f);
          float p = __expf(ngam * s);
          int off = (row * 256 + (g * 64 + 16 * wc + l15) * 2) ^ ((row & 7) << 4);
          *(uint16_t*)(pB + off) = f2bf(p);
        }
      }
    }
    __syncthreads();

#pragma unroll
    for (int kk = 0; kk < 4; ++kk) {
      bf16x8 pa[2];
#pragma unroll
      for (int m = 0; m < 2; ++m) {
        int row = 32 * wr + 16 * m + l15;
        int off = (row * 256 + kk * 64 + l4 * 16) ^ ((row & 7) << 4);
        pa[m] = *(const bf16x8*)(pB + off);
      }
      int krow = c0 + kk * 32 + l4 * 8;
#pragma unroll
      for (int n = 0; n < 4; ++n) {
        int j = colb * BNf + wc * 64 + 16 * n + l15;
        bf16x8 bm;
        if (USE_NT) {
          bm = *(const bf16x8*)(nT + (size_t)j * Cc + krow);
        } else {
          u16x8 tt;
#pragma unroll
          for (int i = 0; i < 8; ++i) tt[i] = f2bf(nrm[(size_t)(krow + i) * Cc + j]);
          bm = __builtin_bit_cast(bf16x8, tt);
        }
        acc[0][n] = mfma_bf16(pa[0], bm, acc[0][n]);
        acc[1][n] = mfma_bf16(pa[1], bm, acc[1][n]);
      }
    }
  }

  float* outBuf = (float*)smem;
  const int orow0 = rowb * BMf;
#pragma unroll
  for (int h = 0; h < 2; ++h) {
    __syncthreads();
    if (wr == h) {
#pragma unroll
      for (int m = 0; m < 2; ++m) {
#pragma unroll
        for (int n = 0; n < 4; ++n) {
#pragma unroll
          for (int r = 0; r < 4; ++r) {
            int rL = 16 * m + l4 * 4 + r;
            outBuf[rL * 256 + wc * 64 + 16 * n + l15] = acc[m][n][r];
          }
        }
      }
    }
    __syncthreads();
#pragma unroll
    for (int i = 0; i < 4; ++i) {
      int ch = tid + 512 * i;
      int rL = ch >> 6;
      int c4 = ch & 63;
      f32x4 v = *(const f32x4*)(outBuf + rL * 256 + c4 * 4);
      *(f32x4*)(out + (size_t)(orow0 + 32 * h + rL) * Cc + colb * BNf + c4 * 4) = v;
    }
  }
}

// ---------------------------------------------------------------------------
extern "C" void kernel_launch(void* const* d_in, const int* in_sizes, int n_in,
                              void* d_out, int out_size, void* d_ws, size_t ws_size,
                              hipStream_t stream) {
  const float* x   = (const float*)d_in[0];  // [131072,128]
  const float* cen = (const float*)d_in[1];  // [1024,128]
  const float* gam = (const float*)d_in[2];  // [1]
  const float* nrm = (const float*)d_in[3];  // [1024,1024]
  float* out = (float*)d_out;

  const size_t cenbB = (size_t)Cc * Dk * 2;            // 256 KB
  const size_t c2B   = (size_t)Cc * 4;                 // 4 KB
  const size_t nT8B  = (size_t)Cc * Cc;                // 1 MB (fp8)
  const size_t nTB   = (size_t)Cc * Cc * 2;            // 2 MB (bf16 fallback)
  const size_t pFull = (size_t)Nrows * Cc;             // 134 MB (fp8)
  const size_t pChB  = (size_t)CH * Cc;                // 16.8 MB (fp8)

  if (ws_size >= cenbB + c2B + nT8B + pFull) {
    uint16_t* cenb = (uint16_t*)d_ws;
    float*    c2   = (float*)((char*)d_ws + cenbB);
    uint8_t*  nT8  = (uint8_t*)((char*)d_ws + cenbB + c2B);
    uint8_t*  Pws  = (uint8_t*)((char*)d_ws + cenbB + c2B + nT8B);
    prep_cen<<<64, 256, 0, stream>>>(cen, cenb, c2);
    prep_nT8<<<256, 256, 0, stream>>>(nrm, nT8);
    kexp2<<<Nrows / 128, 512, KEXP2_LDS, stream>>>(x, gam, cenb, c2, Pws, 0);
    g2f8<<<(Nrows / 256) * 4, 512, 65536, stream>>>(Pws, nT8, out, 0, Nrows / 256);
  } else if (ws_size >= cenbB + c2B + nT8B + pChB) {
    uint16_t* cenb = (uint16_t*)d_ws;
    float*    c2   = (float*)((char*)d_ws + cenbB);
    uint8_t*  nT8  = (uint8_t*)((char*)d_ws + cenbB + c2B);
    uint8_t*  Pws  = (uint8_t*)((char*)d_ws + cenbB + c2B + nT8B);
    prep_cen<<<64, 256, 0, stream>>>(cen, cenb, c2);
    prep_nT8<<<256, 256, 0, stream>>>(nrm, nT8);
    for (int c = 0; c < NCHUNK; ++c) {
      kexp2<<<CH / 128, 512, KEXP2_LDS, stream>>>(x, gam, cenb, c2, Pws, c * CH);
      g2f8<<<(CH / 256) * 4, 512, 65536, stream>>>(Pws, nT8, out, c * CH, CH / 256);
    }
  } else if (ws_size >= cenbB + c2B + nTB) {
    uint16_t* cenb = (uint16_t*)d_ws;
    float*    c2   = (float*)((char*)d_ws + cenbB);
    uint16_t* nT   = (uint16_t*)((char*)d_ws + cenbB + c2B);
    prep_cen<<<64, 256, 0, stream>>>(cen, cenb, c2);
    prep_nT<<<256, 256, 0, stream>>>(nrm, nT);
    nyst_main<1><<<(Nrows / BMf) * (Cc / BNf), 512, LDS_MAIN, stream>>>(
        x, cen, gam, nrm, cenb, c2, nT, out);
  } else {
    nyst_main<0><<<(Nrows / BMf) * (Cc / BNf), 512, LDS_FB, stream>>>(
        x, cen, gam, nrm, nullptr, nullptr, nullptr, out);
  }
}

// Round 20
// 308.260 us; speedup vs baseline: 2.5621x; 1.0394x over previous
//
#include <hip/hip_runtime.h>
#include <hip/hip_fp8.h>
#include <stdint.h>

typedef float    f32x4  __attribute__((ext_vector_type(4)));
typedef float    f32x16 __attribute__((ext_vector_type(16)));
typedef int      i32x4  __attribute__((ext_vector_type(4)));
typedef int      i32x8  __attribute__((ext_vector_type(8)));
typedef __bf16   bf16x8 __attribute__((ext_vector_type(8)));
typedef uint16_t u16x8  __attribute__((ext_vector_type(8)));
typedef uint16_t u16x4  __attribute__((ext_vector_type(4)));
typedef uint8_t  u8x4   __attribute__((ext_vector_type(4)));
typedef uint32_t u32x4  __attribute__((ext_vector_type(4)));

static __device__ __forceinline__ f32x4 mfma_bf16(bf16x8 a, bf16x8 b, f32x4 c) {
  return __builtin_amdgcn_mfma_f32_16x16x32_bf16(a, b, c, 0, 0, 0);
}
// fp32 -> bf16 round-to-nearest-even
static __device__ __forceinline__ uint16_t f2bf(float f) {
  uint32_t u = __builtin_bit_cast(uint32_t, f);
  u += 0x7fffu + ((u >> 16) & 1u);
  return (uint16_t)(u >> 16);
}
// fp32 -> fp8 OCP e4m3fn
static __device__ __forceinline__ uint8_t f2fp8(float f) {
  __hip_fp8_e4m3 v(f);
  return v.__x;
}
// async global->LDS, 16B per lane (gfx950). dest must be linear-in-lane.
static __device__ __forceinline__ void gload16(const void* src, void* lds) {
  __builtin_amdgcn_global_load_lds(
      (const __attribute__((address_space(1))) void*)src,
      (__attribute__((address_space(3))) void*)lds, 16, 0, 0);
}

constexpr int Nrows = 131072;
constexpr int Dk    = 128;
constexpr int Cc    = 1024;
constexpr int CH     = 16384;          // rows per chunk (mid-ws fallback)
constexpr int NCHUNK = Nrows / CH;     // 8
// fused fallback (R5) geometry
constexpr int BMf   = 64;
constexpr int BNf   = 256;
constexpr int KBf   = 128;
constexpr int XBYTES = BMf * Dk * 2;
constexpr int PBYTES = BMf * KBf * 2;
constexpr int LDS_MAIN = XBYTES + PBYTES + BMf * 4;
constexpr int LDS_FB   = LDS_MAIN + Cc * 4;
constexpr int KEXP2_LDS = 32768 * 3 + 128 * 144 + 512;   // 116864
constexpr int G2F8_LDS  = 131072;                        // 4 x 32 KB tiles

// ---------------------------------------------------------------------------
// Prep A: centers -> bf16 [C][D], and c2[C]
// ---------------------------------------------------------------------------
__global__ void prep_cen(const float* __restrict__ cen,
                         uint16_t* __restrict__ cenb,
                         float* __restrict__ c2) {
  const int t = threadIdx.x;
  const int row = blockIdx.x * 16 + (t >> 4);
  const int q = t & 15;
  const float* src = cen + (size_t)row * Dk + q * 8;
  f32x4 v0 = *(const f32x4*)src;
  f32x4 v1 = *(const f32x4*)(src + 4);
  u16x8 h;
  float ss = 0.f;
#pragma unroll
  for (int i = 0; i < 4; ++i) {
    h[i]     = f2bf(v0[i]); ss += v0[i] * v0[i];
    h[i + 4] = f2bf(v1[i]); ss += v1[i] * v1[i];
  }
  *(u16x8*)(cenb + (size_t)row * Dk + q * 8) = h;
  ss += __shfl_xor(ss, 1);
  ss += __shfl_xor(ss, 2);
  ss += __shfl_xor(ss, 4);
  ss += __shfl_xor(ss, 8);
  if (q == 0) c2[row] = ss;
}

// ---------------------------------------------------------------------------
// Prep B8: nT8_swz[j][...] = fp8(norm[c][j]), chunk-permuted within each
// 128-B K-group by chunk ^ (j&7) (both-sides swizzle source; matches g2f8's
// 128-B-row LDS tiles where the row term contributes 0 to the bank quad).
// ---------------------------------------------------------------------------
__global__ void prep_nT8(const float* __restrict__ nrm, uint8_t* __restrict__ nT8) {
  __shared__ float tile[64][65];
  const int jb = blockIdx.x & 15;
  const int cb = blockIdx.x >> 4;
  const int t  = threadIdx.x;
  const int r  = t >> 4;
  const int q  = t & 15;
#pragma unroll
  for (int i = 0; i < 4; ++i) {
    int row = r + i * 16;
    f32x4 v = *(const f32x4*)(nrm + (size_t)(cb * 64 + row) * Cc + jb * 64 + q * 4);
#pragma unroll
    for (int s = 0; s < 4; ++s) tile[row][q * 4 + s] = v[s];
  }
  __syncthreads();
#pragma unroll
  for (int i = 0; i < 4; ++i) {
    int j = r + i * 16;                  // row within jb tile; (jb*64+j)&7 == j&7
    u8x4 hs;
#pragma unroll
    for (int s = 0; s < 4; ++s) hs[s] = f2fp8(tile[q * 4 + s][j]);
    int c   = ((cb & 1) << 2) | (q >> 2);   // 16-B chunk within 128-B group
    int dc  = c ^ (j & 7);
    int col = (cb >> 1) * 128 + dc * 16 + (q & 3) * 4;
    *(u8x4*)(nT8 + (size_t)(jb * 64 + j) * Cc + col) = hs;
  }
}

// ---------------------------------------------------------------------------
// Prep B (bf16, smallest-ws fused fallback only)
// ---------------------------------------------------------------------------
__global__ void prep_nT(const float* __restrict__ nrm, uint16_t* __restrict__ nT) {
  __shared__ float tile[64][65];
  const int jb = blockIdx.x & 15;
  const int cb = blockIdx.x >> 4;
  const int t  = threadIdx.x;
  const int r  = t >> 4;
  const int q  = t & 15;
#pragma unroll
  for (int i = 0; i < 4; ++i) {
    int row = r + i * 16;
    f32x4 v = *(const f32x4*)(nrm + (size_t)(cb * 64 + row) * Cc + jb * 64 + q * 4);
#pragma unroll
    for (int s = 0; s < 4; ++s) tile[row][q * 4 + s] = v[s];
  }
  __syncthreads();
#pragma unroll
  for (int i = 0; i < 4; ++i) {
    int j = r + i * 16;
    u16x4 hs;
#pragma unroll
    for (int s = 0; s < 4; ++s) hs[s] = f2bf(tile[q * 4 + s][j]);
    *(u16x4*)(nT + (size_t)(jb * 64 + j) * Cc + cb * 64 + q * 4) = hs;
  }
}

// ---------------------------------------------------------------------------
// kexp2: one block per 128-row stripe; colb-loop INSIDE (x read once).
// GEMM1 in bf16 (proven). P stored fp8 e4m3 with chunk ^ (row&7) permutation
// within each 128-B K-group (matches g2f8's BK=128 layout); writes remain
// 128-B-segment coalesced since the permutation stays inside the segment.
// ---------------------------------------------------------------------------
__global__ __launch_bounds__(512, 2) void kexp2(
    const float* __restrict__ x, const float* __restrict__ gam,
    const uint16_t* __restrict__ cenb, const float* __restrict__ c2g,
    uint8_t* __restrict__ P, int row0) {
  extern __shared__ char smem[];
  char*    xB   = smem;                           // [128] rows x 16 chunks, swz
  char*    cB0  = smem + 32768;
  char*    cB1  = smem + 65536;
  uint8_t* pbuf = (uint8_t*)(smem + 98304);       // [128][144] u8
  float*   x2s  = (float*)(smem + 98304 + 128 * 144); // [128]

  const int tid  = threadIdx.x;
  const int lane = tid & 63;
  const int wid  = tid >> 6;     // 0..7
  const int wr   = wid >> 2;     // 0..1 : 64-row half
  const int wn   = wid & 3;      // 0..3 : 32-col quarter
  const int l15  = lane & 15;
  const int l4   = lane >> 4;
  const int mb   = blockIdx.x;

  auto stage_c = [&](char* db, int ct) {
#pragma unroll
    for (int i = 0; i < 4; ++i) {
      int ch = tid + i * 512;    // 2048 chunks of 16B
      int r  = ch >> 4;
      int c  = ch & 15;
      gload16(cenb + (size_t)(ct * 128 + r) * Dk + ((c ^ (r & 7)) * 8),
              db + ch * 16);
    }
  };
  stage_c(cB0, 0);  // prologue: tile 0 in flight under the x staging below

  // ---- stage x (f32 -> bf16, swizzled) + x2 row sums ----
  const float* xblk = x + (size_t)(row0 + mb * 128) * Dk;
#pragma unroll
  for (int it = 0; it < 4; ++it) {
    int ch = tid + it * 512;
    int r  = ch >> 4;
    int cc = ch & 15;
    const float* src = xblk + r * Dk + cc * 8;
    f32x4 v0 = __builtin_nontemporal_load((const f32x4*)src);
    f32x4 v1 = __builtin_nontemporal_load((const f32x4*)(src + 4));
    u16x8 hh;
    float ss = 0.f;
#pragma unroll
    for (int i = 0; i < 4; ++i) {
      hh[i]     = f2bf(v0[i]); ss += v0[i] * v0[i];
      hh[i + 4] = f2bf(v1[i]); ss += v1[i] * v1[i];
    }
    *(u16x8*)(xB + r * 256 + ((cc ^ (r & 7)) * 16)) = hh;
    ss += __shfl_xor(ss, 1);
    ss += __shfl_xor(ss, 2);
    ss += __shfl_xor(ss, 4);
    ss += __shfl_xor(ss, 8);
    if ((tid & 15) == 0) x2s[r] = ss;
  }

  const float ngam = -gam[0];

  for (int ct = 0; ct < 8; ++ct) {
    char* cC = (ct & 1) ? cB1 : cB0;
    char* cN = (ct & 1) ? cB0 : cB1;
    if (ct < 7) stage_c(cN, ct + 1);
    if (ct == 0 || ct == 7) asm volatile("s_waitcnt vmcnt(4)" ::: "memory");
    else                    asm volatile("s_waitcnt vmcnt(8)" ::: "memory");
    __builtin_amdgcn_s_barrier();

    f32x4 cr[4][2];
#pragma unroll
    for (int m = 0; m < 4; ++m)
#pragma unroll
      for (int n = 0; n < 2; ++n) cr[m][n] = f32x4{0.f, 0.f, 0.f, 0.f};

#pragma unroll
    for (int kk = 0; kk < 4; ++kk) {
      bf16x8 aF[4], bF[2];
#pragma unroll
      for (int m = 0; m < 4; ++m) {
        int row = wr * 64 + m * 16 + l15;
        aF[m] = *(const bf16x8*)(xB + row * 256 +
                                 (((kk * 4 + l4) ^ (row & 7)) * 16));
      }
#pragma unroll
      for (int n = 0; n < 2; ++n) {
        int col = wn * 32 + n * 16 + l15;
        bF[n] = *(const bf16x8*)(cC + col * 256 +
                                 (((kk * 4 + l4) ^ (col & 7)) * 16));
      }
#pragma unroll
      for (int m = 0; m < 4; ++m)
#pragma unroll
        for (int n = 0; n < 2; ++n) cr[m][n] = mfma_bf16(aF[m], bF[n], cr[m][n]);
    }

    float c2v[2];
#pragma unroll
    for (int n = 0; n < 2; ++n) c2v[n] = c2g[ct * 128 + wn * 32 + n * 16 + l15];
#pragma unroll
    for (int m = 0; m < 4; ++m) {
#pragma unroll
      for (int n = 0; n < 2; ++n) {
#pragma unroll
        for (int rr = 0; rr < 4; ++rr) {
          int row = wr * 64 + m * 16 + l4 * 4 + rr;
          float s = fmaxf(fmaf(-2.f, cr[m][n][rr], x2s[row] + c2v[n]), 0.f);
          pbuf[row * 144 + wn * 32 + n * 16 + l15] = f2fp8(__expf(ngam * s));
        }
      }
    }
    __builtin_amdgcn_s_barrier();
    // coalesced copy pbuf -> P_swz: permute 16-B chunks within the 128-B group
#pragma unroll
    for (int it = 0; it < 2; ++it) {
      int ch = tid + it * 512;
      int r  = ch >> 3;
      int c  = ch & 7;                 // 16-B chunk within this ct 128-B group
      int dc = c ^ (r & 7);
      *(u32x4*)(P + (size_t)(mb * 128 + r) * Cc + ct * 128 + dc * 16) =
          *(const u32x4*)(pbuf + r * 144 + c * 16);
    }
  }
}

// ---------------------------------------------------------------------------
// g2f8 v7 (BK=128): out = P_swz(fp8) @ nT8_swz^T (fp8), MX MFMA 32x32x64,
// unit scales, 256x256 tile, 8 waves. BARRIER AMORTIZATION: K-step doubled
// to 128 -> 8 K-tiles, 2 barriers each = 16 sync events/block (was 32).
// Occupancy already floor-bound at 1 block/CU, so the 128 KB LDS costs
// nothing. Staging stays linear gload_lds (4 loads/thread per 32 KB tile,
// vmcnt(4) steady); fragment reads use chunk ^ (row&7) over the 8-chunk
// 128-B rows -> 8 lanes/bank-quad across all 8 quads (b128-optimal).
// ---------------------------------------------------------------------------
__global__ __launch_bounds__(512, 2) void g2f8(
    const uint8_t* __restrict__ P, const uint8_t* __restrict__ nT8,
    float* __restrict__ out, int row0, int mblocks) {
  extern __shared__ char smem[];
  char* a0 = smem;              // [256][128] fp8 (pre-swizzled chunk content)
  char* b0 = smem + 32768;
  char* a1 = smem + 65536;
  char* b1 = smem + 98304;      // ends 131072

  const int tid  = threadIdx.x;
  const int lane = tid & 63;
  const int wid  = tid >> 6;      // 0..7
  const int wm   = wid >> 2;      // 0..1
  const int wn   = wid & 3;       // 0..3
  const int l31  = lane & 31;
  const int lh   = lane >> 5;     // 0..1

  // bijective XCD swizzle (nwg % 8 == 0): nb fastest within an XCD's chunk.
  const int nwg  = mblocks * 4;
  const int cpx  = nwg >> 3;
  const int wgid = (blockIdx.x & 7) * cpx + (blockIdx.x >> 3);
  const int nb   = wgid & 3;
  const int mb   = wgid >> 2;

  const uint8_t* Abase = P + (size_t)mb * 256 * Cc;
  const uint8_t* Bbase = nT8 + (size_t)nb * 256 * Cc;

  // stage one 32 KB tile: 2048 chunks of 16B, 4/thread, linear both sides
  auto stage = [&](const uint8_t* gb, char* db, int k0) {
#pragma unroll
    for (int i = 0; i < 4; ++i) {
      int ch = tid + i * 512;
      int r  = ch >> 3;          // row 0..255 (128 B rows)
      int c  = ch & 7;
      gload16(gb + (size_t)r * Cc + k0 + c * 16, db + ch * 16);
    }
  };

  // fragment read offsets (loop-invariant): chunk ^ (row&7) addressing
  int offA[4][2][2], offB[2][2][2];
#pragma unroll
  for (int m = 0; m < 4; ++m) {
    int row = wm * 128 + m * 32 + l31;
    int s = row & 7;
#pragma unroll
    for (int g = 0; g < 2; ++g)
#pragma unroll
      for (int j = 0; j < 2; ++j)
        offA[m][g][j] = row * 128 + (((g * 4 + 2 * lh + j) ^ s) * 16);
  }
#pragma unroll
  for (int n = 0; n < 2; ++n) {
    int row = wn * 64 + n * 32 + l31;
    int s = row & 7;
#pragma unroll
    for (int g = 0; g < 2; ++g)
#pragma unroll
      for (int j = 0; j < 2; ++j)
        offB[n][g][j] = row * 128 + (((g * 4 + 2 * lh + j) ^ s) * 16);
  }
  auto ldfrag = [&](const char* base, const int (&off)[2]) -> i32x8 {
    i32x4 lo = *(const i32x4*)(base + off[0]);
    i32x4 hi = *(const i32x4*)(base + off[1]);
    return __builtin_shufflevector(lo, hi, 0, 1, 2, 3, 4, 5, 6, 7);
  };

  f32x16 acc[4][2];
#pragma unroll
  for (int m = 0; m < 4; ++m)
#pragma unroll
    for (int n = 0; n < 2; ++n)
#pragma unroll
      for (int r = 0; r < 16; ++r) acc[m][n][r] = 0.f;

  // prologue: B(0), A(0), B(1) -> 12 outstanding loads/thread
  stage(Bbase, b0, 0);
  stage(Abase, a0, 0);
  stage(Bbase, b1, 128);

  for (int kt = 0; kt < 8; ++kt) {
    const int q = kt & 1;
    char* aC = q ? a1 : a0;
    char* bC = q ? b1 : b0;
    char* aN = q ? a0 : a1;

    // A(kt),B(kt) landed; newest 4 loads (next B) may stay in flight
    if (kt == 7) asm volatile("s_waitcnt vmcnt(0)" ::: "memory");
    else         asm volatile("s_waitcnt vmcnt(4)" ::: "memory");
    __builtin_amdgcn_s_barrier();                 // BARRIER1

    if (kt + 1 < 8) stage(Abase, aN, (kt + 1) * 128);

    // consume B(kt) into registers (both 64-B K-groups)
    i32x8 bF[2][2];  // [n][g]
#pragma unroll
    for (int n = 0; n < 2; ++n)
#pragma unroll
      for (int g = 0; g < 2; ++g) bF[n][g] = ldfrag(bC, offB[n][g]);

    // m = 0, both groups, under setprio
    __builtin_amdgcn_s_setprio(1);
#pragma unroll
    for (int g = 0; g < 2; ++g) {
      i32x8 aF = ldfrag(aC, offA[0][g]);
      acc[0][0] = __builtin_amdgcn_mfma_scale_f32_32x32x64_f8f6f4(
          aF, bF[0][g], acc[0][0], 0, 0, 0, 127, 0, 127);
      acc[0][1] = __builtin_amdgcn_mfma_scale_f32_32x32x64_f8f6f4(
          aF, bF[1][g], acc[0][1], 0, 0, 0, 127, 0, 127);
    }
    __builtin_amdgcn_s_setprio(0);
    __builtin_amdgcn_s_barrier();                 // BARRIER2: bC free
    if (kt + 2 < 8) stage(Bbase, bC, (kt + 2) * 128);

    // m = 1..3 x both groups: straight-line; compiler pipelines A-reads
    __builtin_amdgcn_s_setprio(1);
#pragma unroll
    for (int m = 1; m < 4; ++m)
#pragma unroll
      for (int g = 0; g < 2; ++g) {
        i32x8 aF = ldfrag(aC, offA[m][g]);
        acc[m][0] = __builtin_amdgcn_mfma_scale_f32_32x32x64_f8f6f4(
            aF, bF[0][g], acc[m][0], 0, 0, 0, 127, 0, 127);
        acc[m][1] = __builtin_amdgcn_mfma_scale_f32_32x32x64_f8f6f4(
            aF, bF[1][g], acc[m][1], 0, 0, 0, 127, 0, 127);
      }
    __builtin_amdgcn_s_setprio(0);
  }

  // epilogue: 4 rounds of 64 rows through a [64][256] f32 bounce (64 KB).
  // C/D 32x32 layout: col=lane&31, row=(reg&3)+8*(reg>>2)+4*(lane>>5).
  float* obuf = (float*)smem;
#pragma unroll
  for (int h = 0; h < 4; ++h) {
    __syncthreads();
    if (wm == (h >> 1)) {
      const int mbase = (h & 1) * 2;
#pragma unroll
      for (int ml = 0; ml < 2; ++ml) {
#pragma unroll
        for (int n = 0; n < 2; ++n) {
#pragma unroll
          for (int r = 0; r < 16; ++r) {
            int rin = (r & 3) + 8 * (r >> 2) + 4 * lh;
            obuf[(ml * 32 + rin) * 256 + wn * 64 + n * 32 + l31] =
                acc[mbase + ml][n][r];
          }
        }
      }
    }
    __syncthreads();
#pragma unroll
    for (int i = 0; i < 8; ++i) {
      int ch = tid + i * 512;   // 4096 chunks of 16B
      int rL = ch >> 6;         // 0..63
      int c4 = ch & 63;
      *(f32x4*)(out + (size_t)(row0 + mb * 256 + h * 64 + rL) * Cc +
                nb * 256 + c4 * 4) = *(const f32x4*)(obuf + rL * 256 + c4 * 4);
    }
  }
}

// ---------------------------------------------------------------------------
// Fused fallback (R5) — only used when ws is too small for the split path.
// ---------------------------------------------------------------------------
template <int USE_NT>
__global__ __launch_bounds__(512, 4) void nyst_main(
    const float* __restrict__ x, const float* __restrict__ cen,
    const float* __restrict__ gam, const float* __restrict__ nrm,
    const uint16_t* __restrict__ cenb, const float* __restrict__ c2g,
    const uint16_t* __restrict__ nT, float* __restrict__ out) {
  extern __shared__ char smem[];
  char*  xB  = smem;
  char*  pB  = smem + XBYTES;
  float* x2s = (float*)(smem + XBYTES + PBYTES);
  float* c2s = (float*)(smem + LDS_MAIN);

  const int tid  = threadIdx.x;
  const int lane = tid & 63;
  const int wid  = tid >> 6;
  const int wr   = wid >> 2;
  const int wc   = wid & 3;
  const int xcd  = blockIdx.x & 7;
  const int bi   = blockIdx.x >> 3;
  const int colb = xcd >> 1;
  const int rowb = (bi << 1) | (xcd & 1);
  const int l15  = lane & 15;
  const int l4   = lane >> 4;

  const float* xblk = x + (size_t)rowb * BMf * Dk;

#pragma unroll
  for (int it = 0; it < 2; ++it) {
    int ch = tid + it * 512;
    int r  = ch >> 4;
    int cc = ch & 15;
    const float* src = xblk + r * Dk + cc * 8;
    f32x4 v0 = __builtin_nontemporal_load((const f32x4*)src);
    f32x4 v1 = __builtin_nontemporal_load((const f32x4*)(src + 4));
    u16x8 hh;
    float ss = 0.f;
#pragma unroll
    for (int i = 0; i < 4; ++i) {
      hh[i]     = f2bf(v0[i]); ss += v0[i] * v0[i];
      hh[i + 4] = f2bf(v1[i]); ss += v1[i] * v1[i];
    }
    int off = (r * 256 + cc * 16) ^ ((r & 7) << 4);
    *(u16x8*)(xB + off) = hh;
    ss += __shfl_xor(ss, 1);
    ss += __shfl_xor(ss, 2);
    ss += __shfl_xor(ss, 4);
    ss += __shfl_xor(ss, 8);
    if ((tid & 15) == 0) x2s[r] = ss;
  }
  if (!USE_NT) {
#pragma unroll
    for (int rr = 0; rr < 2; ++rr) {
      int r = tid + rr * 512;
      const float* src = cen + (size_t)r * Dk;
      float ss = 0.f;
      for (int k = 0; k < Dk / 4; ++k) {
        f32x4 v = *(const f32x4*)(src + 4 * k);
        ss += v[0] * v[0] + v[1] * v[1] + v[2] * v[2] + v[3] * v[3];
      }
      c2s[r] = ss;
    }
  }
  __syncthreads();

  const float ngam = -gam[0];
  f32x4 zero4 = {0.f, 0.f, 0.f, 0.f};
  f32x4 acc[2][4];
#pragma unroll
  for (int m = 0; m < 2; ++m)
#pragma unroll
    for (int n = 0; n < 4; ++n) acc[m][n] = zero4;

  for (int c0 = 0; c0 < Cc; c0 += KBf) {
    f32x4 cr[2][2];
#pragma unroll
    for (int g = 0; g < 2; ++g)
#pragma unroll
      for (int m = 0; m < 2; ++m) cr[g][m] = zero4;

#pragma unroll
    for (int kk = 0; kk < 4; ++kk) {
      bf16x8 b0, b1;
      if (USE_NT) {
        int c0col = c0 + 16 * wc + l15;
        b0 = *(const bf16x8*)(cenb + (size_t)c0col * Dk + kk * 32 + l4 * 8);
        b1 = *(const bf16x8*)(cenb + (size_t)(c0col + 64) * Dk + kk * 32 + l4 * 8);
      } else {
#pragma unroll
        for (int g = 0; g < 2; ++g) {
          int ccol = c0 + g * 64 + 16 * wc + l15;
          const float* cb_ = cen + (size_t)ccol * Dk + kk * 32 + l4 * 8;
          f32x4 v0 = *(const f32x4*)cb_;
          f32x4 v1 = *(const f32x4*)(cb_ + 4);
          u16x8 tt;
#pragma unroll
          for (int i = 0; i < 4; ++i) { tt[i] = f2bf(v0[i]); tt[i + 4] = f2bf(v1[i]); }
          if (g == 0) b0 = __builtin_bit_cast(bf16x8, tt);
          else        b1 = __builtin_bit_cast(bf16x8, tt);
        }
      }
#pragma unroll
      for (int m = 0; m < 2; ++m) {
        int row = 32 * wr + 16 * m + l15;
        int off = (row * 256 + kk * 64 + l4 * 16) ^ ((row & 7) << 4);
        bf16x8 a = *(const bf16x8*)(xB + off);
        cr[0][m] = mfma_bf16(a, b0, cr[0][m]);
        cr[1][m] = mfma_bf16(a, b1, cr[1][m]);
      }
    }

    __syncthreads();
#pragma unroll
    for (int g = 0; g < 2; ++g) {
      int ccol = c0 + g * 64 + 16 * wc + l15;
      float c2v = USE_NT ? c2g[ccol] : c2s[ccol];
#pragma unroll
      for (int m = 0; m < 2; ++m) {
#pragma unroll
        for (int r = 0; r < 4; ++r) {
          int row = 32 * wr + 16 * m + l4 * 4 + r;
          float s = fmaxf(fmaf(-2.f, cr[g][m][r], x2s[row] + c2v), 0.f);
          float p = __expf(ngam * s);
          int off = (row * 256 + (g * 64 + 16 * wc + l15) * 2) ^ ((row & 7) << 4);
          *(uint16_t*)(pB + off) = f2bf(p);
        }
      }
    }
    __syncthreads();

#pragma unroll
    for (int kk = 0; kk < 4; ++kk) {
      bf16x8 pa[2];
#pragma unroll
      for (int m = 0; m < 2; ++m) {
        int row = 32 * wr + 16 * m + l15;
        int off = (row * 256 + kk * 64 + l4 * 16) ^ ((row & 7) << 4);
        pa[m] = *(const bf16x8*)(pB + off);
      }
      int krow = c0 + kk * 32 + l4 * 8;
#pragma unroll
      for (int n = 0; n < 4; ++n) {
        int j = colb * BNf + wc * 64 + 16 * n + l15;
        bf16x8 bm;
        if (USE_NT) {
          bm = *(const bf16x8*)(nT + (size_t)j * Cc + krow);
        } else {
          u16x8 tt;
#pragma unroll
          for (int i = 0; i < 8; ++i) tt[i] = f2bf(nrm[(size_t)(krow + i) * Cc + j]);
          bm = __builtin_bit_cast(bf16x8, tt);
        }
        acc[0][n] = mfma_bf16(pa[0], bm, acc[0][n]);
        acc[1][n] = mfma_bf16(pa[1], bm, acc[1][n]);
      }
    }
  }

  float* outBuf = (float*)smem;
  const int orow0 = rowb * BMf;
#pragma unroll
  for (int h = 0; h < 2; ++h) {
    __syncthreads();
    if (wr == h) {
#pragma unroll
      for (int m = 0; m < 2; ++m) {
#pragma unroll
        for (int n = 0; n < 4; ++n) {
#pragma unroll
          for (int r = 0; r < 4; ++r) {
            int rL = 16 * m + l4 * 4 + r;
            outBuf[rL * 256 + wc * 64 + 16 * n + l15] = acc[m][n][r];
          }
        }
      }
    }
    __syncthreads();
#pragma unroll
    for (int i = 0; i < 4; ++i) {
      int ch = tid + 512 * i;
      int rL = ch >> 6;
      int c4 = ch & 63;
      f32x4 v = *(const f32x4*)(outBuf + rL * 256 + c4 * 4);
      *(f32x4*)(out + (size_t)(orow0 + 32 * h + rL) * Cc + colb * BNf + c4 * 4) = v;
    }
  }
}

// ---------------------------------------------------------------------------
extern "C" void kernel_launch(void* const* d_in, const int* in_sizes, int n_in,
                              void* d_out, int out_size, void* d_ws, size_t ws_size,
                              hipStream_t stream) {
  const float* x   = (const float*)d_in[0];  // [131072,128]
  const float* cen = (const float*)d_in[1];  // [1024,128]
  const float* gam = (const float*)d_in[2];  // [1]
  const float* nrm = (const float*)d_in[3];  // [1024,1024]
  float* out = (float*)d_out;

  const size_t cenbB = (size_t)Cc * Dk * 2;            // 256 KB
  const size_t c2B   = (size_t)Cc * 4;                 // 4 KB
  const size_t nT8B  = (size_t)Cc * Cc;                // 1 MB (fp8)
  const size_t nTB   = (size_t)Cc * Cc * 2;            // 2 MB (bf16 fallback)
  const size_t pFull = (size_t)Nrows * Cc;             // 134 MB (fp8)
  const size_t pChB  = (size_t)CH * Cc;                // 16.8 MB (fp8)

  if (ws_size >= cenbB + c2B + nT8B + pFull) {
    uint16_t* cenb = (uint16_t*)d_ws;
    float*    c2   = (float*)((char*)d_ws + cenbB);
    uint8_t*  nT8  = (uint8_t*)((char*)d_ws + cenbB + c2B);
    uint8_t*  Pws  = (uint8_t*)((char*)d_ws + cenbB + c2B + nT8B);
    prep_cen<<<64, 256, 0, stream>>>(cen, cenb, c2);
    prep_nT8<<<256, 256, 0, stream>>>(nrm, nT8);
    kexp2<<<Nrows / 128, 512, KEXP2_LDS, stream>>>(x, gam, cenb, c2, Pws, 0);
    g2f8<<<(Nrows / 256) * 4, 512, G2F8_LDS, stream>>>(Pws, nT8, out, 0, Nrows / 256);
  } else if (ws_size >= cenbB + c2B + nT8B + pChB) {
    uint16_t* cenb = (uint16_t*)d_ws;
    float*    c2   = (float*)((char*)d_ws + cenbB);
    uint8_t*  nT8  = (uint8_t*)((char*)d_ws + cenbB + c2B);
    uint8_t*  Pws  = (uint8_t*)((char*)d_ws + cenbB + c2B + nT8B);
    prep_cen<<<64, 256, 0, stream>>>(cen, cenb, c2);
    prep_nT8<<<256, 256, 0, stream>>>(nrm, nT8);
    for (int c = 0; c < NCHUNK; ++c) {
      kexp2<<<CH / 128, 512, KEXP2_LDS, stream>>>(x, gam, cenb, c2, Pws, c * CH);
      g2f8<<<(CH / 256) * 4, 512, G2F8_LDS, stream>>>(Pws, nT8, out, c * CH, CH / 256);
    }
  } else if (ws_size >= cenbB + c2B + nTB) {
    uint16_t* cenb = (uint16_t*)d_ws;
    float*    c2   = (float*)((char*)d_ws + cenbB);
    uint16_t* nT   = (uint16_t*)((char*)d_ws + cenbB + c2B);
    prep_cen<<<64, 256, 0, stream>>>(cen, cenb, c2);
    prep_nT<<<256, 256, 0, stream>>>(nrm, nT);
    nyst_main<1><<<(Nrows / BMf) * (Cc / BNf), 512, LDS_MAIN, stream>>>(
        x, cen, gam, nrm, cenb, c2, nT, out);
  } else {
    nyst_main<0><<<(Nrows / BMf) * (Cc / BNf), 512, LDS_FB, stream>>>(
        x, cen, gam, nrm, nullptr, nullptr, nullptr, out);
  }
}

// Round 22
// 306.206 us; speedup vs baseline: 2.5793x; 1.0067x over previous
//
#include <hip/hip_runtime.h>
#include <hip/hip_fp8.h>
#include <stdint.h>

typedef float    f32x4  __attribute__((ext_vector_type(4)));
typedef float    f32x16 __attribute__((ext_vector_type(16)));
typedef int      i32x4  __attribute__((ext_vector_type(4)));
typedef int      i32x8  __attribute__((ext_vector_type(8)));
typedef __bf16   bf16x8 __attribute__((ext_vector_type(8)));
typedef uint16_t u16x8  __attribute__((ext_vector_type(8)));
typedef uint16_t u16x4  __attribute__((ext_vector_type(4)));
typedef uint8_t  u8x4   __attribute__((ext_vector_type(4)));
typedef uint32_t u32x4  __attribute__((ext_vector_type(4)));

static __device__ __forceinline__ f32x4 mfma_bf16(bf16x8 a, bf16x8 b, f32x4 c) {
  return __builtin_amdgcn_mfma_f32_16x16x32_bf16(a, b, c, 0, 0, 0);
}
// fp32 -> bf16 round-to-nearest-even
static __device__ __forceinline__ uint16_t f2bf(float f) {
  uint32_t u = __builtin_bit_cast(uint32_t, f);
  u += 0x7fffu + ((u >> 16) & 1u);
  return (uint16_t)(u >> 16);
}
// fp32 -> fp8 OCP e4m3fn
static __device__ __forceinline__ uint8_t f2fp8(float f) {
  __hip_fp8_e4m3 v(f);
  return v.__x;
}
// async global->LDS, 16B per lane (gfx950). dest must be linear-in-lane.
static __device__ __forceinline__ void gload16(const void* src, void* lds) {
  __builtin_amdgcn_global_load_lds(
      (const __attribute__((address_space(1))) void*)src,
      (__attribute__((address_space(3))) void*)lds, 16, 0, 0);
}

constexpr int Nrows = 131072;
constexpr int Dk    = 128;
constexpr int Cc    = 1024;
constexpr int CH     = 16384;          // rows per chunk (mid-ws fallback)
constexpr int NCHUNK = Nrows / CH;     // 8
// fused fallback (R5) geometry
constexpr int BMf   = 64;
constexpr int BNf   = 256;
constexpr int KBf   = 128;
constexpr int XBYTES = BMf * Dk * 2;
constexpr int PBYTES = BMf * KBf * 2;
constexpr int LDS_MAIN = XBYTES + PBYTES + BMf * 4;
constexpr int LDS_FB   = LDS_MAIN + Cc * 4;
constexpr int KEXP2_LDS = 32768 * 3 + 128 * 144 + 512;   // 116864
constexpr int G2F8_LDS  = 131072;                        // 4 x 32 KB tiles

// ---------------------------------------------------------------------------
// Prep A: centers -> bf16 [C][D], and c2[C]
// ---------------------------------------------------------------------------
__global__ void prep_cen(const float* __restrict__ cen,
                         uint16_t* __restrict__ cenb,
                         float* __restrict__ c2) {
  const int t = threadIdx.x;
  const int row = blockIdx.x * 16 + (t >> 4);
  const int q = t & 15;
  const float* src = cen + (size_t)row * Dk + q * 8;
  f32x4 v0 = *(const f32x4*)src;
  f32x4 v1 = *(const f32x4*)(src + 4);
  u16x8 h;
  float ss = 0.f;
#pragma unroll
  for (int i = 0; i < 4; ++i) {
    h[i]     = f2bf(v0[i]); ss += v0[i] * v0[i];
    h[i + 4] = f2bf(v1[i]); ss += v1[i] * v1[i];
  }
  *(u16x8*)(cenb + (size_t)row * Dk + q * 8) = h;
  ss += __shfl_xor(ss, 1);
  ss += __shfl_xor(ss, 2);
  ss += __shfl_xor(ss, 4);
  ss += __shfl_xor(ss, 8);
  if (q == 0) c2[row] = ss;
}

// ---------------------------------------------------------------------------
// Prep B8: nT8_swz[j][...] = fp8(norm[c][j]), chunk-permuted within each
// 128-B K-group by chunk ^ (j&7) (matches g2f8's BK=128 LDS tiles where the
// row term contributes 0 to the bank quad).
// ---------------------------------------------------------------------------
__global__ void prep_nT8(const float* __restrict__ nrm, uint8_t* __restrict__ nT8) {
  __shared__ float tile[64][65];
  const int jb = blockIdx.x & 15;
  const int cb = blockIdx.x >> 4;
  const int t  = threadIdx.x;
  const int r  = t >> 4;
  const int q  = t & 15;
#pragma unroll
  for (int i = 0; i < 4; ++i) {
    int row = r + i * 16;
    f32x4 v = *(const f32x4*)(nrm + (size_t)(cb * 64 + row) * Cc + jb * 64 + q * 4);
#pragma unroll
    for (int s = 0; s < 4; ++s) tile[row][q * 4 + s] = v[s];
  }
  __syncthreads();
#pragma unroll
  for (int i = 0; i < 4; ++i) {
    int j = r + i * 16;                  // row within jb tile; (jb*64+j)&7 == j&7
    u8x4 hs;
#pragma unroll
    for (int s = 0; s < 4; ++s) hs[s] = f2fp8(tile[q * 4 + s][j]);
    int c   = ((cb & 1) << 2) | (q >> 2);   // 16-B chunk within 128-B group
    int dc  = c ^ (j & 7);
    int col = (cb >> 1) * 128 + dc * 16 + (q & 3) * 4;
    *(u8x4*)(nT8 + (size_t)(jb * 64 + j) * Cc + col) = hs;
  }
}

// ---------------------------------------------------------------------------
// Prep B (bf16, smallest-ws fused fallback only)
// ---------------------------------------------------------------------------
__global__ void prep_nT(const float* __restrict__ nrm, uint16_t* __restrict__ nT) {
  __shared__ float tile[64][65];
  const int jb = blockIdx.x & 15;
  const int cb = blockIdx.x >> 4;
  const int t  = threadIdx.x;
  const int r  = t >> 4;
  const int q  = t & 15;
#pragma unroll
  for (int i = 0; i < 4; ++i) {
    int row = r + i * 16;
    f32x4 v = *(const f32x4*)(nrm + (size_t)(cb * 64 + row) * Cc + jb * 64 + q * 4);
#pragma unroll
    for (int s = 0; s < 4; ++s) tile[row][q * 4 + s] = v[s];
  }
  __syncthreads();
#pragma unroll
  for (int i = 0; i < 4; ++i) {
    int j = r + i * 16;
    u16x4 hs;
#pragma unroll
    for (int s = 0; s < 4; ++s) hs[s] = f2bf(tile[q * 4 + s][j]);
    *(u16x4*)(nT + (size_t)(jb * 64 + j) * Cc + cb * 64 + q * 4) = hs;
  }
}

// ---------------------------------------------------------------------------
// kexp2: one block per 128-row stripe; colb-loop INSIDE (x read once).
// GEMM1 in bf16 (proven). P stored fp8 e4m3 with chunk ^ (row&7) permutation
// within each 128-B K-group (matches g2f8's BK=128 layout); writes remain
// 128-B-segment coalesced since the permutation stays inside the segment.
// ---------------------------------------------------------------------------
__global__ __launch_bounds__(512, 2) void kexp2(
    const float* __restrict__ x, const float* __restrict__ gam,
    const uint16_t* __restrict__ cenb, const float* __restrict__ c2g,
    uint8_t* __restrict__ P, int row0) {
  extern __shared__ char smem[];
  char*    xB   = smem;                           // [128] rows x 16 chunks, swz
  char*    cB0  = smem + 32768;
  char*    cB1  = smem + 65536;
  uint8_t* pbuf = (uint8_t*)(smem + 98304);       // [128][144] u8
  float*   x2s  = (float*)(smem + 98304 + 128 * 144); // [128]

  const int tid  = threadIdx.x;
  const int lane = tid & 63;
  const int wid  = tid >> 6;     // 0..7
  const int wr   = wid >> 2;     // 0..1 : 64-row half
  const int wn   = wid & 3;      // 0..3 : 32-col quarter
  const int l15  = lane & 15;
  const int l4   = lane >> 4;
  const int mb   = blockIdx.x;

  auto stage_c = [&](char* db, int ct) {
#pragma unroll
    for (int i = 0; i < 4; ++i) {
      int ch = tid + i * 512;    // 2048 chunks of 16B
      int r  = ch >> 4;
      int c  = ch & 15;
      gload16(cenb + (size_t)(ct * 128 + r) * Dk + ((c ^ (r & 7)) * 8),
              db + ch * 16);
    }
  };
  stage_c(cB0, 0);  // prologue: tile 0 in flight under the x staging below

  // ---- stage x (f32 -> bf16, swizzled) + x2 row sums ----
  const float* xblk = x + (size_t)(row0 + mb * 128) * Dk;
#pragma unroll
  for (int it = 0; it < 4; ++it) {
    int ch = tid + it * 512;
    int r  = ch >> 4;
    int cc = ch & 15;
    const float* src = xblk + r * Dk + cc * 8;
    f32x4 v0 = __builtin_nontemporal_load((const f32x4*)src);
    f32x4 v1 = __builtin_nontemporal_load((const f32x4*)(src + 4));
    u16x8 hh;
    float ss = 0.f;
#pragma unroll
    for (int i = 0; i < 4; ++i) {
      hh[i]     = f2bf(v0[i]); ss += v0[i] * v0[i];
      hh[i + 4] = f2bf(v1[i]); ss += v1[i] * v1[i];
    }
    *(u16x8*)(xB + r * 256 + ((cc ^ (r & 7)) * 16)) = hh;
    ss += __shfl_xor(ss, 1);
    ss += __shfl_xor(ss, 2);
    ss += __shfl_xor(ss, 4);
    ss += __shfl_xor(ss, 8);
    if ((tid & 15) == 0) x2s[r] = ss;
  }

  const float ngam = -gam[0];

  for (int ct = 0; ct < 8; ++ct) {
    char* cC = (ct & 1) ? cB1 : cB0;
    char* cN = (ct & 1) ? cB0 : cB1;
    if (ct < 7) stage_c(cN, ct + 1);
    if (ct == 0 || ct == 7) asm volatile("s_waitcnt vmcnt(4)" ::: "memory");
    else                    asm volatile("s_waitcnt vmcnt(8)" ::: "memory");
    __builtin_amdgcn_s_barrier();

    f32x4 cr[4][2];
#pragma unroll
    for (int m = 0; m < 4; ++m)
#pragma unroll
      for (int n = 0; n < 2; ++n) cr[m][n] = f32x4{0.f, 0.f, 0.f, 0.f};

#pragma unroll
    for (int kk = 0; kk < 4; ++kk) {
      bf16x8 aF[4], bF[2];
#pragma unroll
      for (int m = 0; m < 4; ++m) {
        int row = wr * 64 + m * 16 + l15;
        aF[m] = *(const bf16x8*)(xB + row * 256 +
                                 (((kk * 4 + l4) ^ (row & 7)) * 16));
      }
#pragma unroll
      for (int n = 0; n < 2; ++n) {
        int col = wn * 32 + n * 16 + l15;
        bF[n] = *(const bf16x8*)(cC + col * 256 +
                                 (((kk * 4 + l4) ^ (col & 7)) * 16));
      }
#pragma unroll
      for (int m = 0; m < 4; ++m)
#pragma unroll
        for (int n = 0; n < 2; ++n) cr[m][n] = mfma_bf16(aF[m], bF[n], cr[m][n]);
    }

    float c2v[2];
#pragma unroll
    for (int n = 0; n < 2; ++n) c2v[n] = c2g[ct * 128 + wn * 32 + n * 16 + l15];
#pragma unroll
    for (int m = 0; m < 4; ++m) {
#pragma unroll
      for (int n = 0; n < 2; ++n) {
#pragma unroll
        for (int rr = 0; rr < 4; ++rr) {
          int row = wr * 64 + m * 16 + l4 * 4 + rr;
          float s = fmaxf(fmaf(-2.f, cr[m][n][rr], x2s[row] + c2v[n]), 0.f);
          pbuf[row * 144 + wn * 32 + n * 16 + l15] = f2fp8(__expf(ngam * s));
        }
      }
    }
    __builtin_amdgcn_s_barrier();
    // coalesced copy pbuf -> P_swz: permute 16-B chunks within the 128-B group
#pragma unroll
    for (int it = 0; it < 2; ++it) {
      int ch = tid + it * 512;
      int r  = ch >> 3;
      int c  = ch & 7;                 // 16-B chunk within this ct 128-B group
      int dc = c ^ (r & 7);
      *(u32x4*)(P + (size_t)(mb * 128 + r) * Cc + ct * 128 + dc * 16) =
          *(const u32x4*)(pbuf + r * 144 + c * 16);
    }
  }
}

// ---------------------------------------------------------------------------
// g2f8 v7 (BK=128): out = P_swz(fp8) @ nT8_swz^T (fp8), MX MFMA 32x32x64,
// unit scales, 256x256 tile, 8 waves. BARRIER AMORTIZATION: K-step doubled
// to 128 -> 8 K-tiles, 2 barriers each = 16 sync events/block (was 32).
// Occupancy already floor-bound at 1 block/CU, so the 128 KB LDS costs
// nothing. Staging stays linear gload_lds (4 loads/thread per 32 KB tile,
// vmcnt(4) steady); fragment reads use chunk ^ (row&7) over the 8-chunk
// 128-B rows -> 8 lanes/bank-quad across all 8 quads (b128-optimal).
// ---------------------------------------------------------------------------
__global__ __launch_bounds__(512, 2) void g2f8(
    const uint8_t* __restrict__ P, const uint8_t* __restrict__ nT8,
    float* __restrict__ out, int row0, int mblocks) {
  extern __shared__ char smem[];
  char* a0 = smem;              // [256][128] fp8 (pre-swizzled chunk content)
  char* b0 = smem + 32768;
  char* a1 = smem + 65536;
  char* b1 = smem + 98304;      // ends 131072

  const int tid  = threadIdx.x;
  const int lane = tid & 63;
  const int wid  = tid >> 6;      // 0..7
  const int wm   = wid >> 2;      // 0..1
  const int wn   = wid & 3;       // 0..3
  const int l31  = lane & 31;
  const int lh   = lane >> 5;     // 0..1

  // bijective XCD swizzle (nwg % 8 == 0): nb fastest within an XCD's chunk.
  const int nwg  = mblocks * 4;
  const int cpx  = nwg >> 3;
  const int wgid = (blockIdx.x & 7) * cpx + (blockIdx.x >> 3);
  const int nb   = wgid & 3;
  const int mb   = wgid >> 2;

  const uint8_t* Abase = P + (size_t)mb * 256 * Cc;
  const uint8_t* Bbase = nT8 + (size_t)nb * 256 * Cc;

  // stage one 32 KB tile: 2048 chunks of 16B, 4/thread, linear both sides
  auto stage = [&](const uint8_t* gb, char* db, int k0) {
#pragma unroll
    for (int i = 0; i < 4; ++i) {
      int ch = tid + i * 512;
      int r  = ch >> 3;          // row 0..255 (128 B rows)
      int c  = ch & 7;
      gload16(gb + (size_t)r * Cc + k0 + c * 16, db + ch * 16);
    }
  };

  // fragment read offsets (loop-invariant): chunk ^ (row&7) addressing
  int offA[4][2][2], offB[2][2][2];
#pragma unroll
  for (int m = 0; m < 4; ++m) {
    int row = wm * 128 + m * 32 + l31;
    int s = row & 7;
#pragma unroll
    for (int g = 0; g < 2; ++g)
#pragma unroll
      for (int j = 0; j < 2; ++j)
        offA[m][g][j] = row * 128 + (((g * 4 + 2 * lh + j) ^ s) * 16);
  }
#pragma unroll
  for (int n = 0; n < 2; ++n) {
    int row = wn * 64 + n * 32 + l31;
    int s = row & 7;
#pragma unroll
    for (int g = 0; g < 2; ++g)
#pragma unroll
      for (int j = 0; j < 2; ++j)
        offB[n][g][j] = row * 128 + (((g * 4 + 2 * lh + j) ^ s) * 16);
  }
  auto ldfrag = [&](const char* base, const int (&off)[2]) -> i32x8 {
    i32x4 lo = *(const i32x4*)(base + off[0]);
    i32x4 hi = *(const i32x4*)(base + off[1]);
    return __builtin_shufflevector(lo, hi, 0, 1, 2, 3, 4, 5, 6, 7);
  };

  f32x16 acc[4][2];
#pragma unroll
  for (int m = 0; m < 4; ++m)
#pragma unroll
    for (int n = 0; n < 2; ++n)
#pragma unroll
      for (int r = 0; r < 16; ++r) acc[m][n][r] = 0.f;

  // prologue: B(0), A(0), B(1) -> 12 outstanding loads/thread
  stage(Bbase, b0, 0);
  stage(Abase, a0, 0);
  stage(Bbase, b1, 128);

  for (int kt = 0; kt < 8; ++kt) {
    const int q = kt & 1;
    char* aC = q ? a1 : a0;
    char* bC = q ? b1 : b0;
    char* aN = q ? a0 : a1;

    // A(kt),B(kt) landed; newest 4 loads (next B) may stay in flight
    if (kt == 7) asm volatile("s_waitcnt vmcnt(0)" ::: "memory");
    else         asm volatile("s_waitcnt vmcnt(4)" ::: "memory");
    __builtin_amdgcn_s_barrier();                 // BARRIER1

    if (kt + 1 < 8) stage(Abase, aN, (kt + 1) * 128);

    // consume B(kt) into registers (both 64-B K-groups)
    i32x8 bF[2][2];  // [n][g]
#pragma unroll
    for (int n = 0; n < 2; ++n)
#pragma unroll
      for (int g = 0; g < 2; ++g) bF[n][g] = ldfrag(bC, offB[n][g]);

    // m = 0, both groups, under setprio
    __builtin_amdgcn_s_setprio(1);
#pragma unroll
    for (int g = 0; g < 2; ++g) {
      i32x8 aF = ldfrag(aC, offA[0][g]);
      acc[0][0] = __builtin_amdgcn_mfma_scale_f32_32x32x64_f8f6f4(
          aF, bF[0][g], acc[0][0], 0, 0, 0, 127, 0, 127);
      acc[0][1] = __builtin_amdgcn_mfma_scale_f32_32x32x64_f8f6f4(
          aF, bF[1][g], acc[0][1], 0, 0, 0, 127, 0, 127);
    }
    __builtin_amdgcn_s_setprio(0);
    __builtin_amdgcn_s_barrier();                 // BARRIER2: bC free
    if (kt + 2 < 8) stage(Bbase, bC, (kt + 2) * 128);

    // m = 1..3 x both groups: straight-line; compiler pipelines A-reads
    __builtin_amdgcn_s_setprio(1);
#pragma unroll
    for (int m = 1; m < 4; ++m)
#pragma unroll
      for (int g = 0; g < 2; ++g) {
        i32x8 aF = ldfrag(aC, offA[m][g]);
        acc[m][0] = __builtin_amdgcn_mfma_scale_f32_32x32x64_f8f6f4(
            aF, bF[0][g], acc[m][0], 0, 0, 0, 127, 0, 127);
        acc[m][1] = __builtin_amdgcn_mfma_scale_f32_32x32x64_f8f6f4(
            aF, bF[1][g], acc[m][1], 0, 0, 0, 127, 0, 127);
      }
    __builtin_amdgcn_s_setprio(0);
  }

  // epilogue: 4 rounds of 64 rows through a [64][256] f32 bounce (64 KB).
  // C/D 32x32 layout: col=lane&31, row=(reg&3)+8*(reg>>2)+4*(lane>>5).
  float* obuf = (float*)smem;
#pragma unroll
  for (int h = 0; h < 4; ++h) {
    __syncthreads();
    if (wm == (h >> 1)) {
      const int mbase = (h & 1) * 2;
#pragma unroll
      for (int ml = 0; ml < 2; ++ml) {
#pragma unroll
        for (int n = 0; n < 2; ++n) {
#pragma unroll
          for (int r = 0; r < 16; ++r) {
            int rin = (r & 3) + 8 * (r >> 2) + 4 * lh;
            obuf[(ml * 32 + rin) * 256 + wn * 64 + n * 32 + l31] =
                acc[mbase + ml][n][r];
          }
        }
      }
    }
    __syncthreads();
#pragma unroll
    for (int i = 0; i < 8; ++i) {
      int ch = tid + i * 512;   // 4096 chunks of 16B
      int rL = ch >> 6;         // 0..63
      int c4 = ch & 63;
      *(f32x4*)(out + (size_t)(row0 + mb * 256 + h * 64 + rL) * Cc +
                nb * 256 + c4 * 4) = *(const f32x4*)(obuf + rL * 256 + c4 * 4);
    }
  }
}

// ---------------------------------------------------------------------------
// Fused fallback (R5) — only used when ws is too small for the split path.
// ---------------------------------------------------------------------------
template <int USE_NT>
__global__ __launch_bounds__(512, 4) void nyst_main(
    const float* __restrict__ x, const float* __restrict__ cen,
    const float* __restrict__ gam, const float* __restrict__ nrm,
    const uint16_t* __restrict__ cenb, const float* __restrict__ c2g,
    const uint16_t* __restrict__ nT, float* __restrict__ out) {
  extern __shared__ char smem[];
  char*  xB  = smem;
  char*  pB  = smem + XBYTES;
  float* x2s = (float*)(smem + XBYTES + PBYTES);
  float* c2s = (float*)(smem + LDS_MAIN);

  const int tid  = threadIdx.x;
  const int lane = tid & 63;
  const int wid  = tid >> 6;
  const int wr   = wid >> 2;
  const int wc   = wid & 3;
  const int xcd  = blockIdx.x & 7;
  const int bi   = blockIdx.x >> 3;
  const int colb = xcd >> 1;
  const int rowb = (bi << 1) | (xcd & 1);
  const int l15  = lane & 15;
  const int l4   = lane >> 4;

  const float* xblk = x + (size_t)rowb * BMf * Dk;

#pragma unroll
  for (int it = 0; it < 2; ++it) {
    int ch = tid + it * 512;
    int r  = ch >> 4;
    int cc = ch & 15;
    const float* src = xblk + r * Dk + cc * 8;
    f32x4 v0 = __builtin_nontemporal_load((const f32x4*)src);
    f32x4 v1 = __builtin_nontemporal_load((const f32x4*)(src + 4));
    u16x8 hh;
    float ss = 0.f;
#pragma unroll
    for (int i = 0; i < 4; ++i) {
      hh[i]     = f2bf(v0[i]); ss += v0[i] * v0[i];
      hh[i + 4] = f2bf(v1[i]); ss += v1[i] * v1[i];
    }
    int off = (r * 256 + cc * 16) ^ ((r & 7) << 4);
    *(u16x8*)(xB + off) = hh;
    ss += __shfl_xor(ss, 1);
    ss += __shfl_xor(ss, 2);
    ss += __shfl_xor(ss, 4);
    ss += __shfl_xor(ss, 8);
    if ((tid & 15) == 0) x2s[r] = ss;
  }
  if (!USE_NT) {
#pragma unroll
    for (int rr = 0; rr < 2; ++rr) {
      int r = tid + rr * 512;
      const float* src = cen + (size_t)r * Dk;
      float ss = 0.f;
      for (int k = 0; k < Dk / 4; ++k) {
        f32x4 v = *(const f32x4*)(src + 4 * k);
        ss += v[0] * v[0] + v[1] * v[1] + v[2] * v[2] + v[3] * v[3];
      }
      c2s[r] = ss;
    }
  }
  __syncthreads();

  const float ngam = -gam[0];
  f32x4 zero4 = {0.f, 0.f, 0.f, 0.f};
  f32x4 acc[2][4];
#pragma unroll
  for (int m = 0; m < 2; ++m)
#pragma unroll
    for (int n = 0; n < 4; ++n) acc[m][n] = zero4;

  for (int c0 = 0; c0 < Cc; c0 += KBf) {
    f32x4 cr[2][2];
#pragma unroll
    for (int g = 0; g < 2; ++g)
#pragma unroll
      for (int m = 0; m < 2; ++m) cr[g][m] = zero4;

#pragma unroll
    for (int kk = 0; kk < 4; ++kk) {
      bf16x8 b0, b1;
      if (USE_NT) {
        int c0col = c0 + 16 * wc + l15;
        b0 = *(const bf16x8*)(cenb + (size_t)c0col * Dk + kk * 32 + l4 * 8);
        b1 = *(const bf16x8*)(cenb + (size_t)(c0col + 64) * Dk + kk * 32 + l4 * 8);
      } else {
#pragma unroll
        for (int g = 0; g < 2; ++g) {
          int ccol = c0 + g * 64 + 16 * wc + l15;
          const float* cb_ = cen + (size_t)ccol * Dk + kk * 32 + l4 * 8;
          f32x4 v0 = *(const f32x4*)cb_;
          f32x4 v1 = *(const f32x4*)(cb_ + 4);
          u16x8 tt;
#pragma unroll
          for (int i = 0; i < 4; ++i) { tt[i] = f2bf(v0[i]); tt[i + 4] = f2bf(v1[i]); }
          if (g == 0) b0 = __builtin_bit_cast(bf16x8, tt);
          else        b1 = __builtin_bit_cast(bf16x8, tt);
        }
      }
#pragma unroll
      for (int m = 0; m < 2; ++m) {
        int row = 32 * wr + 16 * m + l15;
        int off = (row * 256 + kk * 64 + l4 * 16) ^ ((row & 7) << 4);
        bf16x8 a = *(const bf16x8*)(xB + off);
        cr[0][m] = mfma_bf16(a, b0, cr[0][m]);
        cr[1][m] = mfma_bf16(a, b1, cr[1][m]);
      }
    }

    __syncthreads();
#pragma unroll
    for (int g = 0; g < 2; ++g) {
      int ccol = c0 + g * 64 + 16 * wc + l15;
      float c2v = USE_NT ? c2g[ccol] : c2s[ccol];
#pragma unroll
      for (int m = 0; m < 2; ++m) {
#pragma unroll
        for (int r = 0; r < 4; ++r) {
          int row = 32 * wr + 16 * m + l4 * 4 + r;
          float s = fmaxf(fmaf(-2.f, cr[g][m][r], x2s[row] + c2v), 0.f);
          float p = __expf(ngam * s);
          int off = (row * 256 + (g * 64 + 16 * wc + l15) * 2) ^ ((row & 7) << 4);
          *(uint16_t*)(pB + off) = f2bf(p);
        }
      }
    }
    __syncthreads();

#pragma unroll
    for (int kk = 0; kk < 4; ++kk) {
      bf16x8 pa[2];
#pragma unroll
      for (int m = 0; m < 2; ++m) {
        int row = 32 * wr + 16 * m + l15;
        int off = (row * 256 + kk * 64 + l4 * 16) ^ ((row & 7) << 4);
        pa[m] = *(const bf16x8*)(pB + off);
      }
      int krow = c0 + kk * 32 + l4 * 8;
#pragma unroll
      for (int n = 0; n < 4; ++n) {
        int j = colb * BNf + wc * 64 + 16 * n + l15;
        bf16x8 bm;
        if (USE_NT) {
          bm = *(const bf16x8*)(nT + (size_t)j * Cc + krow);
        } else {
          u16x8 tt;
#pragma unroll
          for (int i = 0; i < 8; ++i) tt[i] = f2bf(nrm[(size_t)(krow + i) * Cc + j]);
          bm = __builtin_bit_cast(bf16x8, tt);
        }
        acc[0][n] = mfma_bf16(pa[0], bm, acc[0][n]);
        acc[1][n] = mfma_bf16(pa[1], bm, acc[1][n]);
      }
    }
  }

  float* outBuf = (float*)smem;
  const int orow0 = rowb * BMf;
#pragma unroll
  for (int h = 0; h < 2; ++h) {
    __syncthreads();
    if (wr == h) {
#pragma unroll
      for (int m = 0; m < 2; ++m) {
#pragma unroll
        for (int n = 0; n < 4; ++n) {
#pragma unroll
          for (int r = 0; r < 4; ++r) {
            int rL = 16 * m + l4 * 4 + r;
            outBuf[rL * 256 + wc * 64 + 16 * n + l15] = acc[m][n][r];
          }
        }
      }
    }
    __syncthreads();
#pragma unroll
    for (int i = 0; i < 4; ++i) {
      int ch = tid + 512 * i;
      int rL = ch >> 6;
      int c4 = ch & 63;
      f32x4 v = *(const f32x4*)(outBuf + rL * 256 + c4 * 4);
      *(f32x4*)(out + (size_t)(orow0 + 32 * h + rL) * Cc + colb * BNf + c4 * 4) = v;
    }
  }
}

// ---------------------------------------------------------------------------
extern "C" void kernel_launch(void* const* d_in, const int* in_sizes, int n_in,
                              void* d_out, int out_size, void* d_ws, size_t ws_size,
                              hipStream_t stream) {
  const float* x   = (const float*)d_in[0];  // [131072,128]
  const float* cen = (const float*)d_in[1];  // [1024,128]
  const float* gam = (const float*)d_in[2];  // [1]
  const float* nrm = (const float*)d_in[3];  // [1024,1024]
  float* out = (float*)d_out;

  const size_t cenbB = (size_t)Cc * Dk * 2;            // 256 KB
  const size_t c2B   = (size_t)Cc * 4;                 // 4 KB
  const size_t nT8B  = (size_t)Cc * Cc;                // 1 MB (fp8)
  const size_t nTB   = (size_t)Cc * Cc * 2;            // 2 MB (bf16 fallback)
  const size_t pFull = (size_t)Nrows * Cc;             // 134 MB (fp8)
  const size_t pChB  = (size_t)CH * Cc;                // 16.8 MB (fp8)

  if (ws_size >= cenbB + c2B + nT8B + pFull) {
    uint16_t* cenb = (uint16_t*)d_ws;
    float*    c2   = (float*)((char*)d_ws + cenbB);
    uint8_t*  nT8  = (uint8_t*)((char*)d_ws + cenbB + c2B);
    uint8_t*  Pws  = (uint8_t*)((char*)d_ws + cenbB + c2B + nT8B);
    prep_cen<<<64, 256, 0, stream>>>(cen, cenb, c2);
    prep_nT8<<<256, 256, 0, stream>>>(nrm, nT8);
    kexp2<<<Nrows / 128, 512, KEXP2_LDS, stream>>>(x, gam, cenb, c2, Pws, 0);
    g2f8<<<(Nrows / 256) * 4, 512, G2F8_LDS, stream>>>(Pws, nT8, out, 0, Nrows / 256);
  } else if (ws_size >= cenbB + c2B + nT8B + pChB) {
    uint16_t* cenb = (uint16_t*)d_ws;
    float*    c2   = (float*)((char*)d_ws + cenbB);
    uint8_t*  nT8  = (uint8_t*)((char*)d_ws + cenbB + c2B);
    uint8_t*  Pws  = (uint8_t*)((char*)d_ws + cenbB + c2B + nT8B);
    prep_cen<<<64, 256, 0, stream>>>(cen, cenb, c2);
    prep_nT8<<<256, 256, 0, stream>>>(nrm, nT8);
    for (int c = 0; c < NCHUNK; ++c) {
      kexp2<<<CH / 128, 512, KEXP2_LDS, stream>>>(x, gam, cenb, c2, Pws, c * CH);
      g2f8<<<(CH / 256) * 4, 512, G2F8_LDS, stream>>>(Pws, nT8, out, c * CH, CH / 256);
    }
  } else if (ws_size >= cenbB + c2B + nTB) {
    uint16_t* cenb = (uint16_t*)d_ws;
    float*    c2   = (float*)((char*)d_ws + cenbB);
    uint16_t* nT   = (uint16_t*)((char*)d_ws + cenbB + c2B);
    prep_cen<<<64, 256, 0, stream>>>(cen, cenb, c2);
    prep_nT<<<256, 256, 0, stream>>>(nrm, nT);
    nyst_main<1><<<(Nrows / BMf) * (Cc / BNf), 512, LDS_MAIN, stream>>>(
        x, cen, gam, nrm, cenb, c2, nT, out);
  } else {
    nyst_main<0><<<(Nrows / BMf) * (Cc / BNf), 512, LDS_FB, stream>>>(
        x, cen, gam, nrm, nullptr, nullptr, nullptr, out);
  }
}